// Round 1
// baseline (13569.426 us; speedup 1.0000x reference)
//
#include <hip/hip_runtime.h>
#include <math.h>
#include <stdint.h>

// Problem constants (B=4, T=4096, D=1024, H=16, DIM=64, L=8, KB=4, R=16, S=128)
#define TT   4096
#define DD   1024
#define HH   16
#define DIMM 64
#define SS   128

// ---------------------------------------------------------------------------
// GEMM: C(16384x1024) = A(16384x1024) @ W(1024x1024), fp32, 64x64 tile.
// MODE 0: QKV projection -> write [b][h][t][d] layout, multiply by mask[row].
// MODE 1: output projection -> row-major C + bias[col].
// ---------------------------------------------------------------------------
template<int MODE>
__global__ __launch_bounds__(256) void gemm_k(
    const float* __restrict__ A, const float* __restrict__ W,
    const float* __restrict__ aux, float* __restrict__ C)
{
    __shared__ float As[16][68];   // [k][m], padded
    __shared__ float Ws[16][68];   // [k][n], padded
    const int tid = threadIdx.x;
    const int bx = blockIdx.x, by = blockIdx.y;
    const int tx = tid & 15, ty = tid >> 4;
    const int row0 = by * 64, col0 = bx * 64;
    const int la_m = tid >> 2,        la_k = (tid & 3) * 4;
    const int lw_k = tid >> 4,        lw_n = (tid & 15) * 4;

    float acc[4][4];
#pragma unroll
    for (int i = 0; i < 4; i++)
#pragma unroll
        for (int j = 0; j < 4; j++) acc[i][j] = 0.f;

    for (int k0 = 0; k0 < 1024; k0 += 16) {
        const float4 av = *(const float4*)&A[(size_t)(row0 + la_m) * 1024 + k0 + la_k];
        const float4 wv = *(const float4*)&W[(size_t)(k0 + lw_k) * 1024 + col0 + lw_n];
        __syncthreads();
        As[la_k + 0][la_m] = av.x;
        As[la_k + 1][la_m] = av.y;
        As[la_k + 2][la_m] = av.z;
        As[la_k + 3][la_m] = av.w;
        *(float4*)&Ws[lw_k][lw_n] = wv;
        __syncthreads();
#pragma unroll
        for (int kk = 0; kk < 16; kk++) {
            const float4 af = *(const float4*)&As[kk][ty * 4];
            const float4 bf = *(const float4*)&Ws[kk][tx * 4];
            const float ar[4] = {af.x, af.y, af.z, af.w};
            const float br[4] = {bf.x, bf.y, bf.z, bf.w};
#pragma unroll
            for (int i = 0; i < 4; i++)
#pragma unroll
                for (int j = 0; j < 4; j++)
                    acc[i][j] = fmaf(ar[i], br[j], acc[i][j]);
        }
    }

    if (MODE == 0) {
        // mask * result -> Q[b][h][t][d]; h is fixed per block (col0 % 64 == 0)
        const int h = col0 >> 6;
        const int d0 = tx * 4;
#pragma unroll
        for (int i = 0; i < 4; i++) {
            const int row = row0 + ty * 4 + i;
            const float mval = aux[row];                 // mask[b*T+t]
            const int b = row >> 12, t = row & (TT - 1);
            float4 v = make_float4(acc[i][0] * mval, acc[i][1] * mval,
                                   acc[i][2] * mval, acc[i][3] * mval);
            *(float4*)&C[(((size_t)(b * HH + h) * TT + t) * DIMM) + d0] = v;
        }
    } else {
        const int c0 = col0 + tx * 4;
        const float4 bv = *(const float4*)&aux[c0];
#pragma unroll
        for (int i = 0; i < 4; i++) {
            const int row = row0 + ty * 4 + i;
            float4 v = make_float4(acc[i][0] + bv.x, acc[i][1] + bv.y,
                                   acc[i][2] + bv.z, acc[i][3] + bv.w);
            *(float4*)&C[(size_t)row * 1024 + c0] = v;
        }
    }
}

// ---------------------------------------------------------------------------
// Assignment: per (b,h) block, for every t compute proj -> tanh -> corner
// logits -> softmax(16) -> top-2 (jax tie-break: lowest index wins) ->
// renormalized weights. Writes 16 (s,w) pairs per token + per-bucket count.
// ---------------------------------------------------------------------------
__global__ __launch_bounds__(256) void assign_k(
    const float* __restrict__ Kb, const float* __restrict__ planesT,
    const float* __restrict__ protosT, const float* __restrict__ logit_temp,
    unsigned char* __restrict__ aIdx, float* __restrict__ aW,
    float* __restrict__ gA)
{
    __shared__ float sPl[64][32];   // planes_T (DIM x L*KB)
    __shared__ float sPr[4][16];    // protos_T (KB x R)
    __shared__ float sCnt[SS];
    const int tid = threadIdx.x;
    const int bh = blockIdx.x;

    for (int i = tid; i < 2048; i += 256) ((float*)sPl)[i] = planesT[i];
    if (tid < 64)  ((float*)sPr)[tid] = protosT[tid];
    if (tid < SS)  sCnt[tid] = 0.f;
    __syncthreads();

    const float scale = fminf(fmaxf(__expf(logit_temp[0]), 0.01f), 20.0f);
    const float inv_scale = 1.0f / scale;
    const float* kbase = Kb + (size_t)bh * (TT * DIMM);

    for (int t = tid; t < TT; t += 256) {
        const float* kr = kbase + t * DIMM;
        float proj[32];
#pragma unroll
        for (int p = 0; p < 32; p++) proj[p] = 0.f;
#pragma unroll 4
        for (int d4 = 0; d4 < 16; d4++) {
            const float4 kv = *(const float4*)&kr[d4 * 4];
            const float* pl = &sPl[d4 * 4][0];
#pragma unroll
            for (int p = 0; p < 32; p++)
                proj[p] += kv.x * pl[p] + kv.y * pl[32 + p] +
                           kv.z * pl[64 + p] + kv.w * pl[96 + p];
        }
#pragma unroll
        for (int p = 0; p < 32; p++) proj[p] = tanhf(proj[p]) * inv_scale;

        unsigned char idx[16];
        float wv[16];
#pragma unroll
        for (int l = 0; l < 8; l++) {
            float g[16];
#pragma unroll
            for (int r = 0; r < 16; r++)
                g[r] = proj[l * 4 + 0] * sPr[0][r] + proj[l * 4 + 1] * sPr[1][r] +
                       proj[l * 4 + 2] * sPr[2][r] + proj[l * 4 + 3] * sPr[3][r];
            float mx = g[0];
#pragma unroll
            for (int r = 1; r < 16; r++) mx = fmaxf(mx, g[r]);
            float Zs = 0.f;
#pragma unroll
            for (int r = 0; r < 16; r++) Zs += __expf(g[r] - mx);
            // top-2 on logits (== top-2 on probs); strict > keeps lowest index on ties
            int a = 0; float ga = g[0];
#pragma unroll
            for (int r = 1; r < 16; r++) { if (g[r] > ga) { ga = g[r]; a = r; } }
            int b2 = (a == 0) ? 1 : 0; float gb = g[b2];
#pragma unroll
            for (int r = 0; r < 16; r++) { if (r != a && g[r] > gb) { gb = g[r]; b2 = r; } }
            const float pa = __expf(ga - mx) / Zs;
            const float pb = __expf(gb - mx) / Zs;
            const float den = pa + pb + 1e-6f;
            const float wa = pa / den, wb = pb / den;
            idx[l * 2 + 0] = (unsigned char)(l * 16 + a);  wv[l * 2 + 0] = wa;
            idx[l * 2 + 1] = (unsigned char)(l * 16 + b2); wv[l * 2 + 1] = wb;
            atomicAdd(&sCnt[l * 16 + a],  wa);
            atomicAdd(&sCnt[l * 16 + b2], wb);
        }
        const size_t off = (size_t)bh * TT + t;
        uint32_t pk[4];
#pragma unroll
        for (int j = 0; j < 4; j++)
            pk[j] = (uint32_t)idx[j * 4] | ((uint32_t)idx[j * 4 + 1] << 8) |
                    ((uint32_t)idx[j * 4 + 2] << 16) | ((uint32_t)idx[j * 4 + 3] << 24);
        uint4 pkv = make_uint4(pk[0], pk[1], pk[2], pk[3]);
        *(uint4*)&aIdx[off * 16] = pkv;
#pragma unroll
        for (int j = 0; j < 4; j++)
            *(float4*)&aW[off * 16 + j * 4] =
                make_float4(wv[j * 4], wv[j * 4 + 1], wv[j * 4 + 2], wv[j * 4 + 3]);
    }
    __syncthreads();
    if (tid < SS) gA[bh * SS + tid] = sCnt[tid];
}

// ---------------------------------------------------------------------------
// Scatter: bucket[s][d] += w * row[d] over all t, in LDS (padded row of 65
// -> bank = (s+d)%32, spreads data-dependent s), then normalize by (A+1e-6).
// Launched twice: once for K, once for V.
// ---------------------------------------------------------------------------
__global__ __launch_bounds__(256) void scatter_k(
    const float* __restrict__ src, const unsigned char* __restrict__ aIdx,
    const float* __restrict__ aW, const float* __restrict__ gA,
    float* __restrict__ gB)
{
    __shared__ float sB[SS][65];
    const int tid = threadIdx.x;
    const int bh = blockIdx.x;
    for (int i = tid; i < SS * 65; i += 256) ((float*)sB)[i] = 0.f;
    __syncthreads();

    const float* sbase = src + (size_t)bh * (TT * DIMM);
    const unsigned char* ib = aIdx + (size_t)bh * TT * 16;
    const float* wb = aW + (size_t)bh * TT * 16;

    for (int t = tid; t < TT; t += 256) {
        int sidx[16]; float w[16];
        const uint4 pk = *(const uint4*)&ib[t * 16];
        const uint32_t pks[4] = {pk.x, pk.y, pk.z, pk.w};
#pragma unroll
        for (int j = 0; j < 4; j++) {
#pragma unroll
            for (int c = 0; c < 4; c++) sidx[j * 4 + c] = (pks[j] >> (8 * c)) & 255;
            const float4 wv = *(const float4*)&wb[t * 16 + j * 4];
            w[j * 4 + 0] = wv.x; w[j * 4 + 1] = wv.y; w[j * 4 + 2] = wv.z; w[j * 4 + 3] = wv.w;
        }
        const float* row = sbase + t * DIMM;
#pragma unroll 4
        for (int d4 = 0; d4 < 16; d4++) {
            const float4 v = *(const float4*)&row[d4 * 4];
#pragma unroll
            for (int p = 0; p < 16; p++) {
                float* bp = &sB[sidx[p]][d4 * 4];
                const float wt = w[p];
                atomicAdd(bp + 0, wt * v.x);
                atomicAdd(bp + 1, wt * v.y);
                atomicAdd(bp + 2, wt * v.z);
                atomicAdd(bp + 3, wt * v.w);
            }
        }
    }
    __syncthreads();
    for (int i = tid; i < SS * DIMM; i += 256) {
        const int s = i >> 6, d = i & 63;
        gB[(size_t)bh * (SS * DIMM) + i] = sB[s][d] / (gA[bh * SS + s] + 1e-6f);
    }
}

// ---------------------------------------------------------------------------
// Attention: per (b,h, t-chunk) block; buckets staged in LDS (64 KB);
// one thread per token, online softmax over 128 buckets.
// Writes att in (b, t, h, d) layout for the final GEMM.
// ---------------------------------------------------------------------------
__global__ __launch_bounds__(256) void attn_k(
    const float* __restrict__ Qb, const float* __restrict__ gBK,
    const float* __restrict__ gBV, float* __restrict__ att)
{
    __shared__ float sBK[SS][DIMM];
    __shared__ float sBV[SS][DIMM];
    const int tid = threadIdx.x;
    const int tc = blockIdx.x;   // t chunk (16)
    const int bh = blockIdx.y;   // (b,h)   (64)
    float* sk = &sBK[0][0];
    float* sv = &sBV[0][0];
    for (int i = tid * 4; i < SS * DIMM; i += 1024) {
        *(float4*)&sk[i] = *(const float4*)&gBK[(size_t)bh * (SS * DIMM) + i];
        *(float4*)&sv[i] = *(const float4*)&gBV[(size_t)bh * (SS * DIMM) + i];
    }
    __syncthreads();

    const int t = tc * 256 + tid;
    const float* q = Qb + (size_t)bh * (TT * DIMM) + (size_t)t * DIMM;
    float qr[64];
#pragma unroll
    for (int d4 = 0; d4 < 16; d4++) {
        const float4 v = *(const float4*)&q[d4 * 4];
        qr[d4 * 4 + 0] = v.x; qr[d4 * 4 + 1] = v.y; qr[d4 * 4 + 2] = v.z; qr[d4 * 4 + 3] = v.w;
    }
    float m = -INFINITY, Z = 0.f, o[64];
#pragma unroll
    for (int d = 0; d < 64; d++) o[d] = 0.f;

    for (int s = 0; s < SS; s++) {
        float sc = 0.f;
#pragma unroll
        for (int d = 0; d < 64; d++) sc = fmaf(qr[d], sBK[s][d], sc);
        sc *= 0.125f;                       // 1/sqrt(64)
        const float nm = fmaxf(m, sc);
        const float corr = __expf(m - nm);  // exp(-inf)=0 on first iter
        const float p = __expf(sc - nm);
        Z = Z * corr + p;
#pragma unroll
        for (int d = 0; d < 64; d++) o[d] = fmaf(p, sBV[s][d], o[d] * corr);
        m = nm;
    }
    const float invZ = 1.0f / Z;
    const int b = bh >> 4, h = bh & 15;
    float* outp = att + (((size_t)b * TT + t) * HH + h) * DIMM;
#pragma unroll
    for (int d4 = 0; d4 < 16; d4++) {
        float4 v = make_float4(o[d4 * 4] * invZ, o[d4 * 4 + 1] * invZ,
                               o[d4 * 4 + 2] * invZ, o[d4 * 4 + 3] * invZ);
        *(float4*)&outp[d4 * 4] = v;
    }
}

// ---------------------------------------------------------------------------
// Launcher. Workspace layout (floats unless noted), ~216 MiB total:
//   Q: 0..16M | K: 16M..32M | V: 32M..48M (reused as att after scatter)
//   gBK: 48M(=3<<24) +512K | gBV +512K | gA +8K | aW +4M floats | aIdx 4MB bytes
// ---------------------------------------------------------------------------
extern "C" void kernel_launch(void* const* d_in, const int* in_sizes, int n_in,
                              void* d_out, int out_size, void* d_ws, size_t ws_size,
                              hipStream_t stream)
{
    const float* x       = (const float*)d_in[0];
    const float* mask    = (const float*)d_in[1];
    const float* Wq      = (const float*)d_in[2];
    const float* Wk      = (const float*)d_in[3];
    const float* Wv      = (const float*)d_in[4];
    const float* Wout    = (const float*)d_in[5];
    const float* b_out   = (const float*)d_in[6];
    const float* planesT = (const float*)d_in[7];
    const float* protosT = (const float*)d_in[8];
    const float* ltemp   = (const float*)d_in[9];
    float* out = (float*)d_out;

    float* ws  = (float*)d_ws;
    float* Qb  = ws;
    float* Kb  = ws + (1u << 24);
    float* Vb  = ws + (2u << 24);
    float* att = Vb;                       // V dead after scatter; alias
    float* gBK = ws + (3u << 24);
    float* gBV = gBK + 524288;
    float* gA  = gBV + 524288;
    float* aW  = gA + 64 * SS;
    unsigned char* aIdx = (unsigned char*)(aW + 4194304);

    const dim3 gg(16, 256);
    gemm_k<0><<<gg, 256, 0, stream>>>(x, Wq, mask, Qb);
    gemm_k<0><<<gg, 256, 0, stream>>>(x, Wk, mask, Kb);
    gemm_k<0><<<gg, 256, 0, stream>>>(x, Wv, mask, Vb);

    assign_k<<<64, 256, 0, stream>>>(Kb, planesT, protosT, ltemp, aIdx, aW, gA);
    scatter_k<<<64, 256, 0, stream>>>(Kb, aIdx, aW, gA, gBK);
    scatter_k<<<64, 256, 0, stream>>>(Vb, aIdx, aW, gA, gBV);

    attn_k<<<dim3(16, 64), 256, 0, stream>>>(Qb, gBK, gBV, att);

    gemm_k<1><<<gg, 256, 0, stream>>>(att, Wout, b_out, out);
}

// Round 2
// 5270.314 us; speedup vs baseline: 2.5747x; 2.5747x over previous
//
#include <hip/hip_runtime.h>
#include <math.h>
#include <stdint.h>

// Problem constants (B=4, T=4096, D=1024, H=16, DIM=64, L=8, KB=4, R=16, S=128)
#define TT   4096
#define DD   1024
#define HH   16
#define DIMM 64
#define SS   128

// ---------------------------------------------------------------------------
// GEMM: C(16384x1024) = A(16384x1024) @ W(1024x1024), fp32, 64x64 tile.
// MODE 0: QKV projection -> write [b][h][t][d] layout, multiply by mask[row].
// MODE 1: output projection -> row-major C + bias[col].
// ---------------------------------------------------------------------------
template<int MODE>
__global__ __launch_bounds__(256) void gemm_k(
    const float* __restrict__ A, const float* __restrict__ W,
    const float* __restrict__ aux, float* __restrict__ C)
{
    __shared__ float As[16][68];   // [k][m], padded
    __shared__ float Ws[16][68];   // [k][n], padded
    const int tid = threadIdx.x;
    const int bx = blockIdx.x, by = blockIdx.y;
    const int tx = tid & 15, ty = tid >> 4;
    const int row0 = by * 64, col0 = bx * 64;
    const int la_m = tid >> 2,        la_k = (tid & 3) * 4;
    const int lw_k = tid >> 4,        lw_n = (tid & 15) * 4;

    float acc[4][4];
#pragma unroll
    for (int i = 0; i < 4; i++)
#pragma unroll
        for (int j = 0; j < 4; j++) acc[i][j] = 0.f;

    for (int k0 = 0; k0 < 1024; k0 += 16) {
        const float4 av = *(const float4*)&A[(size_t)(row0 + la_m) * 1024 + k0 + la_k];
        const float4 wv = *(const float4*)&W[(size_t)(k0 + lw_k) * 1024 + col0 + lw_n];
        __syncthreads();
        As[la_k + 0][la_m] = av.x;
        As[la_k + 1][la_m] = av.y;
        As[la_k + 2][la_m] = av.z;
        As[la_k + 3][la_m] = av.w;
        *(float4*)&Ws[lw_k][lw_n] = wv;
        __syncthreads();
#pragma unroll
        for (int kk = 0; kk < 16; kk++) {
            const float4 af = *(const float4*)&As[kk][ty * 4];
            const float4 bf = *(const float4*)&Ws[kk][tx * 4];
            const float ar[4] = {af.x, af.y, af.z, af.w};
            const float br[4] = {bf.x, bf.y, bf.z, bf.w};
#pragma unroll
            for (int i = 0; i < 4; i++)
#pragma unroll
                for (int j = 0; j < 4; j++)
                    acc[i][j] = fmaf(ar[i], br[j], acc[i][j]);
        }
    }

    if (MODE == 0) {
        // mask * result -> Q[b][h][t][d]; h is fixed per block (col0 % 64 == 0)
        const int h = col0 >> 6;
        const int d0 = tx * 4;
#pragma unroll
        for (int i = 0; i < 4; i++) {
            const int row = row0 + ty * 4 + i;
            const float mval = aux[row];                 // mask[b*T+t]
            const int b = row >> 12, t = row & (TT - 1);
            float4 v = make_float4(acc[i][0] * mval, acc[i][1] * mval,
                                   acc[i][2] * mval, acc[i][3] * mval);
            *(float4*)&C[(((size_t)(b * HH + h) * TT + t) * DIMM) + d0] = v;
        }
    } else {
        const int c0 = col0 + tx * 4;
        const float4 bv = *(const float4*)&aux[c0];
#pragma unroll
        for (int i = 0; i < 4; i++) {
            const int row = row0 + ty * 4 + i;
            float4 v = make_float4(acc[i][0] + bv.x, acc[i][1] + bv.y,
                                   acc[i][2] + bv.z, acc[i][3] + bv.w);
            *(float4*)&C[(size_t)row * 1024 + c0] = v;
        }
    }
}

// ---------------------------------------------------------------------------
// Assignment: per (b,h) block, for every t compute proj -> tanh -> corner
// logits -> softmax(16) -> top-2 (jax tie-break: lowest index wins) ->
// renormalized weights. Writes 16 (s,w) pairs per token + per-bucket count.
// ---------------------------------------------------------------------------
__global__ __launch_bounds__(256) void assign_k(
    const float* __restrict__ Kb, const float* __restrict__ planesT,
    const float* __restrict__ protosT, const float* __restrict__ logit_temp,
    unsigned char* __restrict__ aIdx, float* __restrict__ aW,
    float* __restrict__ gA)
{
    __shared__ float sPl[64][32];   // planes_T (DIM x L*KB)
    __shared__ float sPr[4][16];    // protos_T (KB x R)
    __shared__ float sCnt[SS];
    const int tid = threadIdx.x;
    const int bh = blockIdx.x;

    for (int i = tid; i < 2048; i += 256) ((float*)sPl)[i] = planesT[i];
    if (tid < 64)  ((float*)sPr)[tid] = protosT[tid];
    if (tid < SS)  sCnt[tid] = 0.f;
    __syncthreads();

    const float scale = fminf(fmaxf(__expf(logit_temp[0]), 0.01f), 20.0f);
    const float inv_scale = 1.0f / scale;
    const float* kbase = Kb + (size_t)bh * (TT * DIMM);

    for (int t = tid; t < TT; t += 256) {
        const float* kr = kbase + t * DIMM;
        float proj[32];
#pragma unroll
        for (int p = 0; p < 32; p++) proj[p] = 0.f;
#pragma unroll 4
        for (int d4 = 0; d4 < 16; d4++) {
            const float4 kv = *(const float4*)&kr[d4 * 4];
            const float* pl = &sPl[d4 * 4][0];
#pragma unroll
            for (int p = 0; p < 32; p++)
                proj[p] += kv.x * pl[p] + kv.y * pl[32 + p] +
                           kv.z * pl[64 + p] + kv.w * pl[96 + p];
        }
#pragma unroll
        for (int p = 0; p < 32; p++) proj[p] = tanhf(proj[p]) * inv_scale;

        unsigned char idx[16];
        float wv[16];
#pragma unroll
        for (int l = 0; l < 8; l++) {
            float g[16];
#pragma unroll
            for (int r = 0; r < 16; r++)
                g[r] = proj[l * 4 + 0] * sPr[0][r] + proj[l * 4 + 1] * sPr[1][r] +
                       proj[l * 4 + 2] * sPr[2][r] + proj[l * 4 + 3] * sPr[3][r];
            float mx = g[0];
#pragma unroll
            for (int r = 1; r < 16; r++) mx = fmaxf(mx, g[r]);
            float Zs = 0.f;
#pragma unroll
            for (int r = 0; r < 16; r++) Zs += __expf(g[r] - mx);
            // top-2 on logits (== top-2 on probs); strict > keeps lowest index on ties
            int a = 0; float ga = g[0];
#pragma unroll
            for (int r = 1; r < 16; r++) { if (g[r] > ga) { ga = g[r]; a = r; } }
            int b2 = (a == 0) ? 1 : 0; float gb = g[b2];
#pragma unroll
            for (int r = 0; r < 16; r++) { if (r != a && g[r] > gb) { gb = g[r]; b2 = r; } }
            const float pa = __expf(ga - mx) / Zs;
            const float pb = __expf(gb - mx) / Zs;
            const float den = pa + pb + 1e-6f;
            const float wa = pa / den, wb = pb / den;
            idx[l * 2 + 0] = (unsigned char)(l * 16 + a);  wv[l * 2 + 0] = wa;
            idx[l * 2 + 1] = (unsigned char)(l * 16 + b2); wv[l * 2 + 1] = wb;
            atomicAdd(&sCnt[l * 16 + a],  wa);
            atomicAdd(&sCnt[l * 16 + b2], wb);
        }
        const size_t off = (size_t)bh * TT + t;
        uint32_t pk[4];
#pragma unroll
        for (int j = 0; j < 4; j++)
            pk[j] = (uint32_t)idx[j * 4] | ((uint32_t)idx[j * 4 + 1] << 8) |
                    ((uint32_t)idx[j * 4 + 2] << 16) | ((uint32_t)idx[j * 4 + 3] << 24);
        uint4 pkv = make_uint4(pk[0], pk[1], pk[2], pk[3]);
        *(uint4*)&aIdx[off * 16] = pkv;
#pragma unroll
        for (int j = 0; j < 4; j++)
            *(float4*)&aW[off * 16 + j * 4] =
                make_float4(wv[j * 4], wv[j * 4 + 1], wv[j * 4 + 2], wv[j * 4 + 3]);
    }
    __syncthreads();
    if (tid < SS) gA[bh * SS + tid] = sCnt[tid];
}

// ---------------------------------------------------------------------------
// Zero-fill the global bucket accumulators (ws is re-poisoned each launch).
// 1024 blocks x 256 threads x 1 float4 = 1,048,576 floats (gBK ++ gBV).
// ---------------------------------------------------------------------------
__global__ __launch_bounds__(256) void zero_k(float* __restrict__ p)
{
    const size_t i = ((size_t)blockIdx.x * 256 + threadIdx.x) * 4;
    *(float4*)&p[i] = make_float4(0.f, 0.f, 0.f, 0.f);
}

// ---------------------------------------------------------------------------
// Fused K+V scatter, split over (t-chunk, bh): 16 x 64 = 1024 blocks.
// Each block: 256 tokens -> LDS-privatized bucket sums (padded row 65 so
// bank = (s+d)%32 spreads data-dependent s), then global atomicAdd partials.
// ---------------------------------------------------------------------------
__global__ __launch_bounds__(256) void scatter2_k(
    const float* __restrict__ Kb, const float* __restrict__ Vb,
    const unsigned char* __restrict__ aIdx, const float* __restrict__ aW,
    float* __restrict__ gBK, float* __restrict__ gBV)
{
    __shared__ float sK[SS][65];
    __shared__ float sV[SS][65];
    const int tid = threadIdx.x;
    const int tc = blockIdx.x;   // t chunk (16)
    const int bh = blockIdx.y;   // (b,h)   (64)

    for (int i = tid; i < SS * 65; i += 256) {
        (&sK[0][0])[i] = 0.f;
        (&sV[0][0])[i] = 0.f;
    }
    __syncthreads();

    const int t = tc * 256 + tid;            // one token per thread
    const size_t off = (size_t)bh * TT + t;

    int sidx[16]; float w[16];
    {
        const uint4 pk = *(const uint4*)&aIdx[off * 16];
        const uint32_t pks[4] = {pk.x, pk.y, pk.z, pk.w};
#pragma unroll
        for (int j = 0; j < 4; j++) {
#pragma unroll
            for (int c = 0; c < 4; c++) sidx[j * 4 + c] = (pks[j] >> (8 * c)) & 255;
            const float4 wv = *(const float4*)&aW[off * 16 + j * 4];
            w[j * 4 + 0] = wv.x; w[j * 4 + 1] = wv.y;
            w[j * 4 + 2] = wv.z; w[j * 4 + 3] = wv.w;
        }
    }

    const float* kr = Kb + (size_t)bh * (TT * DIMM) + (size_t)t * DIMM;
    const float* vr = Vb + (size_t)bh * (TT * DIMM) + (size_t)t * DIMM;

#pragma unroll 2
    for (int d4 = 0; d4 < 16; d4++) {
        const float4 kv = *(const float4*)&kr[d4 * 4];
        const float4 vv = *(const float4*)&vr[d4 * 4];
#pragma unroll
        for (int p = 0; p < 16; p++) {
            const float wt = w[p];
            float* bK = &sK[sidx[p]][d4 * 4];
            atomicAdd(bK + 0, wt * kv.x);
            atomicAdd(bK + 1, wt * kv.y);
            atomicAdd(bK + 2, wt * kv.z);
            atomicAdd(bK + 3, wt * kv.w);
            float* bV = &sV[sidx[p]][d4 * 4];
            atomicAdd(bV + 0, wt * vv.x);
            atomicAdd(bV + 1, wt * vv.y);
            atomicAdd(bV + 2, wt * vv.z);
            atomicAdd(bV + 3, wt * vv.w);
        }
    }
    __syncthreads();

    // combine partials (16 blocks per bh contend per address — cheap)
    for (int i = tid; i < SS * DIMM; i += 256) {
        const int s = i >> 6, d = i & 63;
        atomicAdd(&gBK[(size_t)bh * (SS * DIMM) + i], sK[s][d]);
        atomicAdd(&gBV[(size_t)bh * (SS * DIMM) + i], sV[s][d]);
    }
}

// ---------------------------------------------------------------------------
// Attention: per (b,h, t-chunk) block; buckets staged in LDS (64 KB) with
// the (A+1e-6) normalization folded into the staging load; one thread per
// token, online softmax over 128 buckets. Writes att in (b, t, h, d) layout.
// ---------------------------------------------------------------------------
__global__ __launch_bounds__(256) void attn_k(
    const float* __restrict__ Qb, const float* __restrict__ gBK,
    const float* __restrict__ gBV, const float* __restrict__ gA,
    float* __restrict__ att)
{
    __shared__ float sBK[SS][DIMM];
    __shared__ float sBV[SS][DIMM];
    const int tid = threadIdx.x;
    const int tc = blockIdx.x;   // t chunk (16)
    const int bh = blockIdx.y;   // (b,h)   (64)
    float* sk = &sBK[0][0];
    float* sv = &sBV[0][0];
    for (int i = tid * 4; i < SS * DIMM; i += 1024) {
        const int s = i >> 6;                          // i%4==0 -> same s for 4 elems
        const float inv = 1.0f / (gA[bh * SS + s] + 1e-6f);
        float4 kv = *(const float4*)&gBK[(size_t)bh * (SS * DIMM) + i];
        float4 vv = *(const float4*)&gBV[(size_t)bh * (SS * DIMM) + i];
        kv.x *= inv; kv.y *= inv; kv.z *= inv; kv.w *= inv;
        vv.x *= inv; vv.y *= inv; vv.z *= inv; vv.w *= inv;
        *(float4*)&sk[i] = kv;
        *(float4*)&sv[i] = vv;
    }
    __syncthreads();

    const int t = tc * 256 + tid;
    const float* q = Qb + (size_t)bh * (TT * DIMM) + (size_t)t * DIMM;
    float qr[64];
#pragma unroll
    for (int d4 = 0; d4 < 16; d4++) {
        const float4 v = *(const float4*)&q[d4 * 4];
        qr[d4 * 4 + 0] = v.x; qr[d4 * 4 + 1] = v.y; qr[d4 * 4 + 2] = v.z; qr[d4 * 4 + 3] = v.w;
    }
    float m = -INFINITY, Z = 0.f, o[64];
#pragma unroll
    for (int d = 0; d < 64; d++) o[d] = 0.f;

    for (int s = 0; s < SS; s++) {
        float sc = 0.f;
#pragma unroll
        for (int d = 0; d < 64; d++) sc = fmaf(qr[d], sBK[s][d], sc);
        sc *= 0.125f;                       // 1/sqrt(64)
        const float nm = fmaxf(m, sc);
        const float corr = __expf(m - nm);  // exp(-inf)=0 on first iter
        const float p = __expf(sc - nm);
        Z = Z * corr + p;
#pragma unroll
        for (int d = 0; d < 64; d++) o[d] = fmaf(p, sBV[s][d], o[d] * corr);
        m = nm;
    }
    const float invZ = 1.0f / Z;
    const int b = bh >> 4, h = bh & 15;
    float* outp = att + (((size_t)b * TT + t) * HH + h) * DIMM;
#pragma unroll
    for (int d4 = 0; d4 < 16; d4++) {
        float4 v = make_float4(o[d4 * 4] * invZ, o[d4 * 4 + 1] * invZ,
                               o[d4 * 4 + 2] * invZ, o[d4 * 4 + 3] * invZ);
        *(float4*)&outp[d4 * 4] = v;
    }
}

// ---------------------------------------------------------------------------
// Launcher. Workspace layout (floats unless noted), ~216 MiB total:
//   Q: 0..16M | K: 16M..32M | V: 32M..48M (reused as att after scatter)
//   gBK: 48M(=3<<24) +512K | gBV +512K | gA +8K | aW +4M floats | aIdx 4MB bytes
// ---------------------------------------------------------------------------
extern "C" void kernel_launch(void* const* d_in, const int* in_sizes, int n_in,
                              void* d_out, int out_size, void* d_ws, size_t ws_size,
                              hipStream_t stream)
{
    const float* x       = (const float*)d_in[0];
    const float* mask    = (const float*)d_in[1];
    const float* Wq      = (const float*)d_in[2];
    const float* Wk      = (const float*)d_in[3];
    const float* Wv      = (const float*)d_in[4];
    const float* Wout    = (const float*)d_in[5];
    const float* b_out   = (const float*)d_in[6];
    const float* planesT = (const float*)d_in[7];
    const float* protosT = (const float*)d_in[8];
    const float* ltemp   = (const float*)d_in[9];
    float* out = (float*)d_out;

    float* ws  = (float*)d_ws;
    float* Qb  = ws;
    float* Kb  = ws + (1u << 24);
    float* Vb  = ws + (2u << 24);
    float* att = Vb;                       // V dead after scatter; alias
    float* gBK = ws + (3u << 24);
    float* gBV = gBK + 524288;
    float* gA  = gBV + 524288;
    float* aW  = gA + 64 * SS;
    unsigned char* aIdx = (unsigned char*)(aW + 4194304);

    const dim3 gg(16, 256);
    zero_k<<<1024, 256, 0, stream>>>(gBK);          // zeros gBK and gBV (contiguous)
    gemm_k<0><<<gg, 256, 0, stream>>>(x, Wq, mask, Qb);
    gemm_k<0><<<gg, 256, 0, stream>>>(x, Wk, mask, Kb);
    gemm_k<0><<<gg, 256, 0, stream>>>(x, Wv, mask, Vb);

    assign_k<<<64, 256, 0, stream>>>(Kb, planesT, protosT, ltemp, aIdx, aW, gA);
    scatter2_k<<<dim3(16, 64), 256, 0, stream>>>(Kb, Vb, aIdx, aW, gBK, gBV);

    attn_k<<<dim3(16, 64), 256, 0, stream>>>(Qb, gBK, gBV, gA, att);

    gemm_k<1><<<gg, 256, 0, stream>>>(att, Wout, b_out, out);
}

// Round 3
// 2563.731 us; speedup vs baseline: 5.2928x; 2.0557x over previous
//
#include <hip/hip_runtime.h>
#include <math.h>
#include <stdint.h>

// Problem constants (B=4, T=4096, D=1024, H=16, DIM=64, L=8, KB=4, R=16, S=128)
#define TT   4096
#define DD   1024
#define HH   16
#define DIMM 64
#define SS   128

// ---------------------------------------------------------------------------
// GEMM: C(16384x1024) = A(16384x1024) @ W(1024x1024), fp32, 64x64 tile.
// MODE 0: QKV projection -> write [b][h][t][d] layout, multiply by mask[row].
// MODE 1: output projection -> row-major C + bias[col].
// ---------------------------------------------------------------------------
template<int MODE>
__global__ __launch_bounds__(256) void gemm_k(
    const float* __restrict__ A, const float* __restrict__ W,
    const float* __restrict__ aux, float* __restrict__ C)
{
    __shared__ float As[16][68];   // [k][m], padded
    __shared__ float Ws[16][68];   // [k][n], padded
    const int tid = threadIdx.x;
    const int bx = blockIdx.x, by = blockIdx.y;
    const int tx = tid & 15, ty = tid >> 4;
    const int row0 = by * 64, col0 = bx * 64;
    const int la_m = tid >> 2,        la_k = (tid & 3) * 4;
    const int lw_k = tid >> 4,        lw_n = (tid & 15) * 4;

    float acc[4][4];
#pragma unroll
    for (int i = 0; i < 4; i++)
#pragma unroll
        for (int j = 0; j < 4; j++) acc[i][j] = 0.f;

    for (int k0 = 0; k0 < 1024; k0 += 16) {
        const float4 av = *(const float4*)&A[(size_t)(row0 + la_m) * 1024 + k0 + la_k];
        const float4 wv = *(const float4*)&W[(size_t)(k0 + lw_k) * 1024 + col0 + lw_n];
        __syncthreads();
        As[la_k + 0][la_m] = av.x;
        As[la_k + 1][la_m] = av.y;
        As[la_k + 2][la_m] = av.z;
        As[la_k + 3][la_m] = av.w;
        *(float4*)&Ws[lw_k][lw_n] = wv;
        __syncthreads();
#pragma unroll
        for (int kk = 0; kk < 16; kk++) {
            const float4 af = *(const float4*)&As[kk][ty * 4];
            const float4 bf = *(const float4*)&Ws[kk][tx * 4];
            const float ar[4] = {af.x, af.y, af.z, af.w};
            const float br[4] = {bf.x, bf.y, bf.z, bf.w};
#pragma unroll
            for (int i = 0; i < 4; i++)
#pragma unroll
                for (int j = 0; j < 4; j++)
                    acc[i][j] = fmaf(ar[i], br[j], acc[i][j]);
        }
    }

    if (MODE == 0) {
        // mask * result -> Q[b][h][t][d]; h is fixed per block (col0 % 64 == 0)
        const int h = col0 >> 6;
        const int d0 = tx * 4;
#pragma unroll
        for (int i = 0; i < 4; i++) {
            const int row = row0 + ty * 4 + i;
            const float mval = aux[row];                 // mask[b*T+t]
            const int b = row >> 12, t = row & (TT - 1);
            float4 v = make_float4(acc[i][0] * mval, acc[i][1] * mval,
                                   acc[i][2] * mval, acc[i][3] * mval);
            *(float4*)&C[(((size_t)(b * HH + h) * TT + t) * DIMM) + d0] = v;
        }
    } else {
        const int c0 = col0 + tx * 4;
        const float4 bv = *(const float4*)&aux[c0];
#pragma unroll
        for (int i = 0; i < 4; i++) {
            const int row = row0 + ty * 4 + i;
            float4 v = make_float4(acc[i][0] + bv.x, acc[i][1] + bv.y,
                                   acc[i][2] + bv.z, acc[i][3] + bv.w);
            *(float4*)&C[(size_t)row * 1024 + c0] = v;
        }
    }
}

// ---------------------------------------------------------------------------
// Zero-fill gBK ++ gBV ++ gA (contiguous, 1,056,768 floats = 1032*256*4).
// ---------------------------------------------------------------------------
__global__ __launch_bounds__(256) void zero_k(float* __restrict__ p)
{
    const size_t i = ((size_t)blockIdx.x * 256 + threadIdx.x) * 4;
    *(float4*)&p[i] = make_float4(0.f, 0.f, 0.f, 0.f);
}

// ---------------------------------------------------------------------------
// Assignment: grid (16 t-chunks, 64 bh); one token per thread.
// proj -> tanh -> corner logits -> softmax(16) -> top-2 (strict >, lowest
// index wins ties) -> renormalized weights. Writes 16 (s,w) pairs per token;
// per-block count partials atomically folded into gA (zeroed by zero_k).
// ---------------------------------------------------------------------------
__global__ __launch_bounds__(256) void assign_k(
    const float* __restrict__ Kb, const float* __restrict__ planesT,
    const float* __restrict__ protosT, const float* __restrict__ logit_temp,
    unsigned char* __restrict__ aIdx, float* __restrict__ aW,
    float* __restrict__ gA)
{
    __shared__ float sPl[64][32];   // planes_T (DIM x L*KB)
    __shared__ float sPr[4][16];    // protos_T (KB x R)
    __shared__ float sCnt[SS];
    const int tid = threadIdx.x;
    const int tc = blockIdx.x;   // 16
    const int bh = blockIdx.y;   // 64

    for (int i = tid; i < 2048; i += 256) ((float*)sPl)[i] = planesT[i];
    if (tid < 64)  ((float*)sPr)[tid] = protosT[tid];
    if (tid < SS)  sCnt[tid] = 0.f;
    __syncthreads();

    const float scale = fminf(fmaxf(__expf(logit_temp[0]), 0.01f), 20.0f);
    const float inv_scale = 1.0f / scale;

    const int t = tc * 256 + tid;
    const float* kr = Kb + (size_t)bh * (TT * DIMM) + (size_t)t * DIMM;
    float proj[32];
#pragma unroll
    for (int p = 0; p < 32; p++) proj[p] = 0.f;
#pragma unroll 4
    for (int d4 = 0; d4 < 16; d4++) {
        const float4 kv = *(const float4*)&kr[d4 * 4];
        const float* pl = &sPl[d4 * 4][0];
#pragma unroll
        for (int p = 0; p < 32; p++)
            proj[p] += kv.x * pl[p] + kv.y * pl[32 + p] +
                       kv.z * pl[64 + p] + kv.w * pl[96 + p];
    }
#pragma unroll
    for (int p = 0; p < 32; p++) proj[p] = tanhf(proj[p]) * inv_scale;

    unsigned char idx[16];
    float wv[16];
#pragma unroll
    for (int l = 0; l < 8; l++) {
        float g[16];
#pragma unroll
        for (int r = 0; r < 16; r++)
            g[r] = proj[l * 4 + 0] * sPr[0][r] + proj[l * 4 + 1] * sPr[1][r] +
                   proj[l * 4 + 2] * sPr[2][r] + proj[l * 4 + 3] * sPr[3][r];
        float mx = g[0];
#pragma unroll
        for (int r = 1; r < 16; r++) mx = fmaxf(mx, g[r]);
        float Zs = 0.f;
#pragma unroll
        for (int r = 0; r < 16; r++) Zs += __expf(g[r] - mx);
        int a = 0; float ga = g[0];
#pragma unroll
        for (int r = 1; r < 16; r++) { if (g[r] > ga) { ga = g[r]; a = r; } }
        int b2 = (a == 0) ? 1 : 0; float gb = g[b2];
#pragma unroll
        for (int r = 0; r < 16; r++) { if (r != a && g[r] > gb) { gb = g[r]; b2 = r; } }
        const float pa = __expf(ga - mx) / Zs;
        const float pb = __expf(gb - mx) / Zs;
        const float den = pa + pb + 1e-6f;
        const float wa = pa / den, wb = pb / den;
        idx[l * 2 + 0] = (unsigned char)(l * 16 + a);  wv[l * 2 + 0] = wa;
        idx[l * 2 + 1] = (unsigned char)(l * 16 + b2); wv[l * 2 + 1] = wb;
        atomicAdd(&sCnt[l * 16 + a],  wa);
        atomicAdd(&sCnt[l * 16 + b2], wb);
    }
    const size_t off = (size_t)bh * TT + t;
    uint32_t pk[4];
#pragma unroll
    for (int j = 0; j < 4; j++)
        pk[j] = (uint32_t)idx[j * 4] | ((uint32_t)idx[j * 4 + 1] << 8) |
                ((uint32_t)idx[j * 4 + 2] << 16) | ((uint32_t)idx[j * 4 + 3] << 24);
    *(uint4*)&aIdx[off * 16] = make_uint4(pk[0], pk[1], pk[2], pk[3]);
#pragma unroll
    for (int j = 0; j < 4; j++)
        *(float4*)&aW[off * 16 + j * 4] =
            make_float4(wv[j * 4], wv[j * 4 + 1], wv[j * 4 + 2], wv[j * 4 + 3]);
    __syncthreads();
    if (tid < SS) atomicAdd(&gA[bh * SS + tid], sCnt[tid]);
}

// ---------------------------------------------------------------------------
// Scatter as dense GEMM: bucket_KV[s][j] = sum_t P[t][s] * KV[t][j].
// Grid (16 t-chunks, 64 bh). Per block: loop 4 sub-chunks of 64 tokens;
// build dense P (64x128) + stage KV=[K|V] (64x128) in LDS; register-tiled
// 8x8 fp32 outer-product per thread (C = 128x128); atomicAdd partials out.
// Row stride 132 floats: 16B-aligned float4 rows, bank offset 4/row.
// ---------------------------------------------------------------------------
__global__ __launch_bounds__(256) void scatter3_k(
    const float* __restrict__ Kb, const float* __restrict__ Vb,
    const unsigned char* __restrict__ aIdx, const float* __restrict__ aW,
    float* __restrict__ gBK, float* __restrict__ gBV)
{
    __shared__ float sP[64][132];    // P[t'][s]
    __shared__ float sKV[64][132];   // KV[t'][j], j<64: K, j>=64: V
    const int tid = threadIdx.x;
    const int tc = blockIdx.x;   // 16
    const int bh = blockIdx.y;   // 64
    const int tx = tid & 15;     // j-tile: cols tx*8..tx*8+7
    const int ty = tid >> 4;     // s-tile: rows ty*8..ty*8+7

    float acc[8][8];
#pragma unroll
    for (int i = 0; i < 8; i++)
#pragma unroll
        for (int j = 0; j < 8; j++) acc[i][j] = 0.f;

    const float* kb = Kb + (size_t)bh * (TT * DIMM);
    const float* vb = Vb + (size_t)bh * (TT * DIMM);

    for (int c = 0; c < 4; c++) {
        const int t0 = tc * 256 + c * 64;
        __syncthreads();                     // previous sub-chunk reads done
        for (int i = tid; i < 64 * 132; i += 256) (&sP[0][0])[i] = 0.f;
        __syncthreads();                     // zero visible before scatter
        // stage KV (coalesced float4) ...
        for (int i = tid; i < 2048; i += 256) {
            const int tt = i >> 5;           // 32 float4 per 128-col row
            const int jj = (i & 31) * 4;
            const float4 v = (jj < 64)
                ? *(const float4*)&kb[(size_t)(t0 + tt) * DIMM + jj]
                : *(const float4*)&vb[(size_t)(t0 + tt) * DIMM + jj - 64];
            *(float4*)&sKV[tt][jj] = v;
        }
        // ... and build P rows (thread-private row per token; 16 distinct s)
        if (tid < 64) {
            const size_t off = (size_t)bh * TT + (t0 + tid);
            const uint4 pk = *(const uint4*)&aIdx[off * 16];
            const uint32_t pks[4] = {pk.x, pk.y, pk.z, pk.w};
#pragma unroll
            for (int j = 0; j < 4; j++) {
                const float4 wv = *(const float4*)&aW[off * 16 + j * 4];
                const float w4[4] = {wv.x, wv.y, wv.z, wv.w};
#pragma unroll
                for (int q = 0; q < 4; q++)
                    sP[tid][(pks[j] >> (8 * q)) & 255] = w4[q];
            }
        }
        __syncthreads();
#pragma unroll 2
        for (int kk = 0; kk < 64; kk++) {
            float pv[8], kv[8];
            *(float4*)&pv[0] = *(const float4*)&sP[kk][ty * 8];
            *(float4*)&pv[4] = *(const float4*)&sP[kk][ty * 8 + 4];
            *(float4*)&kv[0] = *(const float4*)&sKV[kk][tx * 8];
            *(float4*)&kv[4] = *(const float4*)&sKV[kk][tx * 8 + 4];
#pragma unroll
            for (int i = 0; i < 8; i++)
#pragma unroll
                for (int j = 0; j < 8; j++)
                    acc[i][j] = fmaf(pv[i], kv[j], acc[i][j]);
        }
    }

    // combine partials (16 blocks per bh contend per address)
#pragma unroll
    for (int i = 0; i < 8; i++) {
        const int s = ty * 8 + i;
#pragma unroll
        for (int j = 0; j < 8; j++) {
            const int col = tx * 8 + j;
            if (col < 64)
                atomicAdd(&gBK[(size_t)bh * (SS * DIMM) + s * DIMM + col], acc[i][j]);
            else
                atomicAdd(&gBV[(size_t)bh * (SS * DIMM) + s * DIMM + (col - 64)], acc[i][j]);
        }
    }
}

// ---------------------------------------------------------------------------
// Attention: per (b,h, t-chunk) block; buckets staged in LDS (64 KB) with
// the (A+1e-6) normalization folded into the staging load; one thread per
// token, online softmax over 128 buckets. Writes att in (b, t, h, d) layout.
// ---------------------------------------------------------------------------
__global__ __launch_bounds__(256) void attn_k(
    const float* __restrict__ Qb, const float* __restrict__ gBK,
    const float* __restrict__ gBV, const float* __restrict__ gA,
    float* __restrict__ att)
{
    __shared__ float sBK[SS][DIMM];
    __shared__ float sBV[SS][DIMM];
    const int tid = threadIdx.x;
    const int tc = blockIdx.x;   // t chunk (16)
    const int bh = blockIdx.y;   // (b,h)   (64)
    float* sk = &sBK[0][0];
    float* sv = &sBV[0][0];
    for (int i = tid * 4; i < SS * DIMM; i += 1024) {
        const int s = i >> 6;
        const float inv = 1.0f / (gA[bh * SS + s] + 1e-6f);
        float4 kv = *(const float4*)&gBK[(size_t)bh * (SS * DIMM) + i];
        float4 vv = *(const float4*)&gBV[(size_t)bh * (SS * DIMM) + i];
        kv.x *= inv; kv.y *= inv; kv.z *= inv; kv.w *= inv;
        vv.x *= inv; vv.y *= inv; vv.z *= inv; vv.w *= inv;
        *(float4*)&sk[i] = kv;
        *(float4*)&sv[i] = vv;
    }
    __syncthreads();

    const int t = tc * 256 + tid;
    const float* q = Qb + (size_t)bh * (TT * DIMM) + (size_t)t * DIMM;
    float qr[64];
#pragma unroll
    for (int d4 = 0; d4 < 16; d4++) {
        const float4 v = *(const float4*)&q[d4 * 4];
        qr[d4 * 4 + 0] = v.x; qr[d4 * 4 + 1] = v.y; qr[d4 * 4 + 2] = v.z; qr[d4 * 4 + 3] = v.w;
    }
    float m = -INFINITY, Z = 0.f, o[64];
#pragma unroll
    for (int d = 0; d < 64; d++) o[d] = 0.f;

    for (int s = 0; s < SS; s++) {
        float sc = 0.f;
#pragma unroll
        for (int d = 0; d < 64; d++) sc = fmaf(qr[d], sBK[s][d], sc);
        sc *= 0.125f;                       // 1/sqrt(64)
        const float nm = fmaxf(m, sc);
        const float corr = __expf(m - nm);  // exp(-inf)=0 on first iter
        const float p = __expf(sc - nm);
        Z = Z * corr + p;
#pragma unroll
        for (int d = 0; d < 64; d++) o[d] = fmaf(p, sBV[s][d], o[d] * corr);
        m = nm;
    }
    const float invZ = 1.0f / Z;
    const int b = bh >> 4, h = bh & 15;
    float* outp = att + (((size_t)b * TT + t) * HH + h) * DIMM;
#pragma unroll
    for (int d4 = 0; d4 < 16; d4++) {
        float4 v = make_float4(o[d4 * 4] * invZ, o[d4 * 4 + 1] * invZ,
                               o[d4 * 4 + 2] * invZ, o[d4 * 4 + 3] * invZ);
        *(float4*)&outp[d4 * 4] = v;
    }
}

// ---------------------------------------------------------------------------
// Launcher. Workspace layout (floats unless noted), ~216 MiB total:
//   Q: 0..16M | K: 16M..32M | V: 32M..48M (reused as att after scatter)
//   gBK: 48M(=3<<24) +512K | gBV +512K | gA +8K | aW +4M floats | aIdx 4MB bytes
// gBK/gBV/gA are contiguous -> single zero_k covers all three.
// ---------------------------------------------------------------------------
extern "C" void kernel_launch(void* const* d_in, const int* in_sizes, int n_in,
                              void* d_out, int out_size, void* d_ws, size_t ws_size,
                              hipStream_t stream)
{
    const float* x       = (const float*)d_in[0];
    const float* mask    = (const float*)d_in[1];
    const float* Wq      = (const float*)d_in[2];
    const float* Wk      = (const float*)d_in[3];
    const float* Wv      = (const float*)d_in[4];
    const float* Wout    = (const float*)d_in[5];
    const float* b_out   = (const float*)d_in[6];
    const float* planesT = (const float*)d_in[7];
    const float* protosT = (const float*)d_in[8];
    const float* ltemp   = (const float*)d_in[9];
    float* out = (float*)d_out;

    float* ws  = (float*)d_ws;
    float* Qb  = ws;
    float* Kb  = ws + (1u << 24);
    float* Vb  = ws + (2u << 24);
    float* att = Vb;                       // V dead after scatter; alias
    float* gBK = ws + (3u << 24);
    float* gBV = gBK + 524288;
    float* gA  = gBV + 524288;
    float* aW  = gA + 64 * SS;
    unsigned char* aIdx = (unsigned char*)(aW + 4194304);

    const dim3 gg(16, 256);
    zero_k<<<1032, 256, 0, stream>>>(gBK);          // zeros gBK ++ gBV ++ gA
    gemm_k<0><<<gg, 256, 0, stream>>>(x, Wq, mask, Qb);
    gemm_k<0><<<gg, 256, 0, stream>>>(x, Wk, mask, Kb);
    gemm_k<0><<<gg, 256, 0, stream>>>(x, Wv, mask, Vb);

    assign_k<<<dim3(16, 64), 256, 0, stream>>>(Kb, planesT, protosT, ltemp, aIdx, aW, gA);
    scatter3_k<<<dim3(16, 64), 256, 0, stream>>>(Kb, Vb, aIdx, aW, gBK, gBV);

    attn_k<<<dim3(16, 64), 256, 0, stream>>>(Qb, gBK, gBV, gA, att);

    gemm_k<1><<<gg, 256, 0, stream>>>(att, Wout, b_out, out);
}

// Round 4
// 1566.298 us; speedup vs baseline: 8.6634x; 1.6368x over previous
//
#include <hip/hip_runtime.h>
#include <math.h>
#include <stdint.h>

// Problem constants (B=4, T=4096, D=1024, H=16, DIM=64, L=8, KB=4, R=16, S=128)
#define TT   4096
#define DD   1024
#define HH   16
#define DIMM 64
#define SS   128

typedef short bf16x8 __attribute__((ext_vector_type(8)));
typedef float f32x4  __attribute__((ext_vector_type(4)));

// fp32 -> bf16 (RNE), finite inputs
__device__ __forceinline__ unsigned short f2bf(float f) {
    uint32_t u = __float_as_uint(f);
    return (unsigned short)((u + 0x7fffu + ((u >> 16) & 1u)) >> 16);
}

// async global->LDS, 16B per lane; LDS dest = uniform base + lane*16
#define GLD16(ldsp, gp) __builtin_amdgcn_global_load_lds( \
    (const __attribute__((address_space(1))) uint32_t*)(gp), \
    (__attribute__((address_space(3))) uint32_t*)(ldsp), 16, 0, 0)

// ---------------------------------------------------------------------------
// cvt: x fp32 -> bf16 (16,777,216 elements). 8 per thread.
// ---------------------------------------------------------------------------
__global__ __launch_bounds__(256) void cvt_k(const float* __restrict__ x,
                                             unsigned short* __restrict__ xb)
{
    const size_t i = ((size_t)blockIdx.x * 256 + threadIdx.x) * 8;
    const float4 a = *(const float4*)&x[i];
    const float4 b = *(const float4*)&x[i + 4];
    uint4 r;
    r.x = (uint32_t)f2bf(a.x) | ((uint32_t)f2bf(a.y) << 16);
    r.y = (uint32_t)f2bf(a.z) | ((uint32_t)f2bf(a.w) << 16);
    r.z = (uint32_t)f2bf(b.x) | ((uint32_t)f2bf(b.y) << 16);
    r.w = (uint32_t)f2bf(b.z) | ((uint32_t)f2bf(b.w) << 16);
    *(uint4*)&xb[i] = r;
}

// ---------------------------------------------------------------------------
// tr: W (1024x1024 fp32, K-major) -> WT (1024x1024 bf16, N-major: WT[n][k]).
// ---------------------------------------------------------------------------
__global__ __launch_bounds__(256) void tr_k(const float* __restrict__ W,
                                            unsigned short* __restrict__ WT)
{
    __shared__ unsigned short tile[32][33];
    const int bx = blockIdx.x * 32;   // W col (=n) base
    const int by = blockIdx.y * 32;   // W row (=k) base
    const int tx = threadIdx.x & 31, ty = threadIdx.x >> 5;  // ty 0..7
#pragma unroll
    for (int r = 0; r < 4; r++) {
        const int row = by + ty * 4 + r;
        tile[tx][ty * 4 + r] = f2bf(W[(size_t)row * 1024 + bx + tx]);
    }
    __syncthreads();
#pragma unroll
    for (int r = 0; r < 4; r++) {
        const int col = bx + ty * 4 + r;
        WT[(size_t)col * 1024 + by + tx] = tile[ty * 4 + r][tx];
    }
}

// ---------------------------------------------------------------------------
// bf16 MFMA GEMM: C(16384x1024) = A(16384x1024 bf16) @ B, B given as
// BT (1024x1024 bf16, BT[n][k]). 128x128 tile, BK=32, 4 waves, each wave a
// 64x64 quadrant via 4x4 grid of mfma_f32_16x16x32_bf16.
// LDS chunk layout: A chunk i (16 rows x 32 k) at i*1024B, lane l's 16B =
// A[i*16+(l&15)][(l>>4)*8 ..+7]  (matches MFMA A-frag: m=lane&15, k=quad*8+j);
// B chunk j at 8192+j*1024B, lane l = B[k=(l>>4)*8..+7][n=j*16+(l&15)].
// Staged with global_load_lds (16B/lane), read back with ds_read_b128.
// MODE 0: epilogue mask[row] -> Qb/Vb in [b][h][t][d].  MODE 1: +bias, row-major.
// ---------------------------------------------------------------------------
template<int MODE>
__global__ __launch_bounds__(256) void mgemm_k(
    const unsigned short* __restrict__ Abf, const unsigned short* __restrict__ BT,
    const float* __restrict__ aux, float* __restrict__ C)
{
    __shared__ short sA[4096];   // 8 KB
    __shared__ short sB[4096];   // 8 KB
    const int tid = threadIdx.x;
    const int w  = tid >> 6;          // wave 0..3
    const int ln = tid & 63;          // lane
    const int wm = w & 1, wn = w >> 1;
    const int row0 = blockIdx.y * 128;
    const int col0 = blockIdx.x * 128;
    const int lr = ln >> 4, lc = ln & 15;

    f32x4 acc[4][4];
#pragma unroll
    for (int i = 0; i < 4; i++)
#pragma unroll
        for (int j = 0; j < 4; j++) acc[i][j] = (f32x4){0.f, 0.f, 0.f, 0.f};

    // staging source offsets for this lane (this wave stages A i=2w,2w+1; B j=2w,2w+1)
    const int ia0 = 2 * w, ia1 = 2 * w + 1;
    const size_t gA0 = (size_t)(row0 + ia0 * 16 + lc) * 1024 + lr * 8;
    const size_t gA1 = (size_t)(row0 + ia1 * 16 + lc) * 1024 + lr * 8;
    const size_t gB0 = (size_t)(col0 + ia0 * 16 + lc) * 1024 + lr * 8;
    const size_t gB1 = (size_t)(col0 + ia1 * 16 + lc) * 1024 + lr * 8;

    for (int k0 = 0; k0 < 1024; k0 += 32) {
        GLD16(&sA[ia0 * 512], Abf + gA0 + k0);
        GLD16(&sA[ia1 * 512], Abf + gA1 + k0);
        GLD16(&sB[ia0 * 512], BT  + gB0 + k0);
        GLD16(&sB[ia1 * 512], BT  + gB1 + k0);
        __syncthreads();                    // drains vmcnt -> LDS tiles ready

        bf16x8 af[4], bfr[4];
#pragma unroll
        for (int ib = 0; ib < 4; ib++)
            af[ib] = *(const bf16x8*)&sA[(wm * 4 + ib) * 512 + ln * 8];
#pragma unroll
        for (int jb = 0; jb < 4; jb++)
            bfr[jb] = *(const bf16x8*)&sB[(wn * 4 + jb) * 512 + ln * 8];
#pragma unroll
        for (int ib = 0; ib < 4; ib++)
#pragma unroll
            for (int jb = 0; jb < 4; jb++)
                acc[ib][jb] = __builtin_amdgcn_mfma_f32_16x16x32_bf16(
                    af[ib], bfr[jb], acc[ib][jb], 0, 0, 0);
        __syncthreads();                    // all reads done before next stage
    }

    if (MODE == 0) {
        const int h = col0 / 64 + wn;       // uniform per wave (col0 mult of 128)
#pragma unroll
        for (int ib = 0; ib < 4; ib++) {
#pragma unroll
            for (int r = 0; r < 4; r++) {
                const int gr = row0 + wm * 64 + ib * 16 + lr * 4 + r;
                const float mval = aux[gr];
                const int b = gr >> 12, t = gr & (TT - 1);
                float* base = C + (((size_t)(b * HH + h) * TT + t) * DIMM);
#pragma unroll
                for (int jb = 0; jb < 4; jb++)
                    base[jb * 16 + lc] = acc[ib][jb][r] * mval;
            }
        }
    } else {
#pragma unroll
        for (int ib = 0; ib < 4; ib++) {
#pragma unroll
            for (int r = 0; r < 4; r++) {
                const int gr = row0 + wm * 64 + ib * 16 + lr * 4 + r;
#pragma unroll
                for (int jb = 0; jb < 4; jb++) {
                    const int col = col0 + wn * 64 + jb * 16 + lc;
                    C[(size_t)gr * 1024 + col] = acc[ib][jb][r] + aux[col];
                }
            }
        }
    }
}

// ---------------------------------------------------------------------------
// fp32 GEMM (kept for K only: assignment top-2 is discrete; bf16-K noise
// (~0.03 on logits) would flip near-degenerate saturated-tanh gaps (~1e-4)
// and move whole token weights between buckets -> breaks threshold).
// ---------------------------------------------------------------------------
template<int MODE>
__global__ __launch_bounds__(256) void gemm_k(
    const float* __restrict__ A, const float* __restrict__ W,
    const float* __restrict__ aux, float* __restrict__ C)
{
    __shared__ float As[16][68];
    __shared__ float Ws[16][68];
    const int tid = threadIdx.x;
    const int bx = blockIdx.x, by = blockIdx.y;
    const int tx = tid & 15, ty = tid >> 4;
    const int row0 = by * 64, col0 = bx * 64;
    const int la_m = tid >> 2,        la_k = (tid & 3) * 4;
    const int lw_k = tid >> 4,        lw_n = (tid & 15) * 4;

    float acc[4][4];
#pragma unroll
    for (int i = 0; i < 4; i++)
#pragma unroll
        for (int j = 0; j < 4; j++) acc[i][j] = 0.f;

    for (int k0 = 0; k0 < 1024; k0 += 16) {
        const float4 av = *(const float4*)&A[(size_t)(row0 + la_m) * 1024 + k0 + la_k];
        const float4 wv = *(const float4*)&W[(size_t)(k0 + lw_k) * 1024 + col0 + lw_n];
        __syncthreads();
        As[la_k + 0][la_m] = av.x;
        As[la_k + 1][la_m] = av.y;
        As[la_k + 2][la_m] = av.z;
        As[la_k + 3][la_m] = av.w;
        *(float4*)&Ws[lw_k][lw_n] = wv;
        __syncthreads();
#pragma unroll
        for (int kk = 0; kk < 16; kk++) {
            const float4 af = *(const float4*)&As[kk][ty * 4];
            const float4 bf = *(const float4*)&Ws[kk][tx * 4];
            const float ar[4] = {af.x, af.y, af.z, af.w};
            const float br[4] = {bf.x, bf.y, bf.z, bf.w};
#pragma unroll
            for (int i = 0; i < 4; i++)
#pragma unroll
                for (int j = 0; j < 4; j++)
                    acc[i][j] = fmaf(ar[i], br[j], acc[i][j]);
        }
    }

    if (MODE == 0) {
        const int h = col0 >> 6;
        const int d0 = tx * 4;
#pragma unroll
        for (int i = 0; i < 4; i++) {
            const int row = row0 + ty * 4 + i;
            const float mval = aux[row];
            const int b = row >> 12, t = row & (TT - 1);
            float4 v = make_float4(acc[i][0] * mval, acc[i][1] * mval,
                                   acc[i][2] * mval, acc[i][3] * mval);
            *(float4*)&C[(((size_t)(b * HH + h) * TT + t) * DIMM) + d0] = v;
        }
    } else {
        const int c0 = col0 + tx * 4;
        const float4 bv = *(const float4*)&aux[c0];
#pragma unroll
        for (int i = 0; i < 4; i++) {
            const int row = row0 + ty * 4 + i;
            float4 v = make_float4(acc[i][0] + bv.x, acc[i][1] + bv.y,
                                   acc[i][2] + bv.z, acc[i][3] + bv.w);
            *(float4*)&C[(size_t)row * 1024 + c0] = v;
        }
    }
}

// ---------------------------------------------------------------------------
// Zero-fill gBK ++ gBV ++ gA (contiguous, 1,056,768 floats = 1032*256*4).
// ---------------------------------------------------------------------------
__global__ __launch_bounds__(256) void zero_k(float* __restrict__ p)
{
    const size_t i = ((size_t)blockIdx.x * 256 + threadIdx.x) * 4;
    *(float4*)&p[i] = make_float4(0.f, 0.f, 0.f, 0.f);
}

// ---------------------------------------------------------------------------
// Assignment (unchanged; reads fp32 Kb).
// ---------------------------------------------------------------------------
__global__ __launch_bounds__(256) void assign_k(
    const float* __restrict__ Kb, const float* __restrict__ planesT,
    const float* __restrict__ protosT, const float* __restrict__ logit_temp,
    unsigned char* __restrict__ aIdx, float* __restrict__ aW,
    float* __restrict__ gA)
{
    __shared__ float sPl[64][32];
    __shared__ float sPr[4][16];
    __shared__ float sCnt[SS];
    const int tid = threadIdx.x;
    const int tc = blockIdx.x;
    const int bh = blockIdx.y;

    for (int i = tid; i < 2048; i += 256) ((float*)sPl)[i] = planesT[i];
    if (tid < 64)  ((float*)sPr)[tid] = protosT[tid];
    if (tid < SS)  sCnt[tid] = 0.f;
    __syncthreads();

    const float scale = fminf(fmaxf(__expf(logit_temp[0]), 0.01f), 20.0f);
    const float inv_scale = 1.0f / scale;

    const int t = tc * 256 + tid;
    const float* kr = Kb + (size_t)bh * (TT * DIMM) + (size_t)t * DIMM;
    float proj[32];
#pragma unroll
    for (int p = 0; p < 32; p++) proj[p] = 0.f;
#pragma unroll 4
    for (int d4 = 0; d4 < 16; d4++) {
        const float4 kv = *(const float4*)&kr[d4 * 4];
        const float* pl = &sPl[d4 * 4][0];
#pragma unroll
        for (int p = 0; p < 32; p++)
            proj[p] += kv.x * pl[p] + kv.y * pl[32 + p] +
                       kv.z * pl[64 + p] + kv.w * pl[96 + p];
    }
#pragma unroll
    for (int p = 0; p < 32; p++) proj[p] = tanhf(proj[p]) * inv_scale;

    unsigned char idx[16];
    float wv[16];
#pragma unroll
    for (int l = 0; l < 8; l++) {
        float g[16];
#pragma unroll
        for (int r = 0; r < 16; r++)
            g[r] = proj[l * 4 + 0] * sPr[0][r] + proj[l * 4 + 1] * sPr[1][r] +
                   proj[l * 4 + 2] * sPr[2][r] + proj[l * 4 + 3] * sPr[3][r];
        float mx = g[0];
#pragma unroll
        for (int r = 1; r < 16; r++) mx = fmaxf(mx, g[r]);
        float Zs = 0.f;
#pragma unroll
        for (int r = 0; r < 16; r++) Zs += __expf(g[r] - mx);
        int a = 0; float ga = g[0];
#pragma unroll
        for (int r = 1; r < 16; r++) { if (g[r] > ga) { ga = g[r]; a = r; } }
        int b2 = (a == 0) ? 1 : 0; float gb = g[b2];
#pragma unroll
        for (int r = 0; r < 16; r++) { if (r != a && g[r] > gb) { gb = g[r]; b2 = r; } }
        const float pa = __expf(ga - mx) / Zs;
        const float pb = __expf(gb - mx) / Zs;
        const float den = pa + pb + 1e-6f;
        const float wa = pa / den, wb = pb / den;
        idx[l * 2 + 0] = (unsigned char)(l * 16 + a);  wv[l * 2 + 0] = wa;
        idx[l * 2 + 1] = (unsigned char)(l * 16 + b2); wv[l * 2 + 1] = wb;
        atomicAdd(&sCnt[l * 16 + a],  wa);
        atomicAdd(&sCnt[l * 16 + b2], wb);
    }
    const size_t off = (size_t)bh * TT + t;
    uint32_t pk[4];
#pragma unroll
    for (int j = 0; j < 4; j++)
        pk[j] = (uint32_t)idx[j * 4] | ((uint32_t)idx[j * 4 + 1] << 8) |
                ((uint32_t)idx[j * 4 + 2] << 16) | ((uint32_t)idx[j * 4 + 3] << 24);
    *(uint4*)&aIdx[off * 16] = make_uint4(pk[0], pk[1], pk[2], pk[3]);
#pragma unroll
    for (int j = 0; j < 4; j++)
        *(float4*)&aW[off * 16 + j * 4] =
            make_float4(wv[j * 4], wv[j * 4 + 1], wv[j * 4 + 2], wv[j * 4 + 3]);
    __syncthreads();
    if (tid < SS) atomicAdd(&gA[bh * SS + tid], sCnt[tid]);
}

// ---------------------------------------------------------------------------
// Scatter as dense GEMM (unchanged).
// ---------------------------------------------------------------------------
__global__ __launch_bounds__(256) void scatter3_k(
    const float* __restrict__ Kb, const float* __restrict__ Vb,
    const unsigned char* __restrict__ aIdx, const float* __restrict__ aW,
    float* __restrict__ gBK, float* __restrict__ gBV)
{
    __shared__ float sP[64][132];
    __shared__ float sKV[64][132];
    const int tid = threadIdx.x;
    const int tc = blockIdx.x;
    const int bh = blockIdx.y;
    const int tx = tid & 15;
    const int ty = tid >> 4;

    float acc[8][8];
#pragma unroll
    for (int i = 0; i < 8; i++)
#pragma unroll
        for (int j = 0; j < 8; j++) acc[i][j] = 0.f;

    const float* kb = Kb + (size_t)bh * (TT * DIMM);
    const float* vb = Vb + (size_t)bh * (TT * DIMM);

    for (int c = 0; c < 4; c++) {
        const int t0 = tc * 256 + c * 64;
        __syncthreads();
        for (int i = tid; i < 64 * 132; i += 256) (&sP[0][0])[i] = 0.f;
        __syncthreads();
        for (int i = tid; i < 2048; i += 256) {
            const int tt = i >> 5;
            const int jj = (i & 31) * 4;
            const float4 v = (jj < 64)
                ? *(const float4*)&kb[(size_t)(t0 + tt) * DIMM + jj]
                : *(const float4*)&vb[(size_t)(t0 + tt) * DIMM + jj - 64];
            *(float4*)&sKV[tt][jj] = v;
        }
        if (tid < 64) {
            const size_t off = (size_t)bh * TT + (t0 + tid);
            const uint4 pk = *(const uint4*)&aIdx[off * 16];
            const uint32_t pks[4] = {pk.x, pk.y, pk.z, pk.w};
#pragma unroll
            for (int j = 0; j < 4; j++) {
                const float4 wv = *(const float4*)&aW[off * 16 + j * 4];
                const float w4[4] = {wv.x, wv.y, wv.z, wv.w};
#pragma unroll
                for (int q = 0; q < 4; q++)
                    sP[tid][(pks[j] >> (8 * q)) & 255] = w4[q];
            }
        }
        __syncthreads();
#pragma unroll 2
        for (int kk = 0; kk < 64; kk++) {
            float pv[8], kv[8];
            *(float4*)&pv[0] = *(const float4*)&sP[kk][ty * 8];
            *(float4*)&pv[4] = *(const float4*)&sP[kk][ty * 8 + 4];
            *(float4*)&kv[0] = *(const float4*)&sKV[kk][tx * 8];
            *(float4*)&kv[4] = *(const float4*)&sKV[kk][tx * 8 + 4];
#pragma unroll
            for (int i = 0; i < 8; i++)
#pragma unroll
                for (int j = 0; j < 8; j++)
                    acc[i][j] = fmaf(pv[i], kv[j], acc[i][j]);
        }
    }

#pragma unroll
    for (int i = 0; i < 8; i++) {
        const int s = ty * 8 + i;
#pragma unroll
        for (int j = 0; j < 8; j++) {
            const int col = tx * 8 + j;
            if (col < 64)
                atomicAdd(&gBK[(size_t)bh * (SS * DIMM) + s * DIMM + col], acc[i][j]);
            else
                atomicAdd(&gBV[(size_t)bh * (SS * DIMM) + s * DIMM + (col - 64)], acc[i][j]);
        }
    }
}

// ---------------------------------------------------------------------------
// Attention (now writes bf16 att in (b, t, h*d) row-major for the out-GEMM).
// ---------------------------------------------------------------------------
__global__ __launch_bounds__(256) void attn_k(
    const float* __restrict__ Qb, const float* __restrict__ gBK,
    const float* __restrict__ gBV, const float* __restrict__ gA,
    unsigned short* __restrict__ attb)
{
    __shared__ float sBK[SS][DIMM];
    __shared__ float sBV[SS][DIMM];
    const int tid = threadIdx.x;
    const int tc = blockIdx.x;
    const int bh = blockIdx.y;
    float* sk = &sBK[0][0];
    float* sv = &sBV[0][0];
    for (int i = tid * 4; i < SS * DIMM; i += 1024) {
        const int s = i >> 6;
        const float inv = 1.0f / (gA[bh * SS + s] + 1e-6f);
        float4 kv = *(const float4*)&gBK[(size_t)bh * (SS * DIMM) + i];
        float4 vv = *(const float4*)&gBV[(size_t)bh * (SS * DIMM) + i];
        kv.x *= inv; kv.y *= inv; kv.z *= inv; kv.w *= inv;
        vv.x *= inv; vv.y *= inv; vv.z *= inv; vv.w *= inv;
        *(float4*)&sk[i] = kv;
        *(float4*)&sv[i] = vv;
    }
    __syncthreads();

    const int t = tc * 256 + tid;
    const float* q = Qb + (size_t)bh * (TT * DIMM) + (size_t)t * DIMM;
    float qr[64];
#pragma unroll
    for (int d4 = 0; d4 < 16; d4++) {
        const float4 v = *(const float4*)&q[d4 * 4];
        qr[d4 * 4 + 0] = v.x; qr[d4 * 4 + 1] = v.y; qr[d4 * 4 + 2] = v.z; qr[d4 * 4 + 3] = v.w;
    }
    float m = -INFINITY, Z = 0.f, o[64];
#pragma unroll
    for (int d = 0; d < 64; d++) o[d] = 0.f;

    for (int s = 0; s < SS; s++) {
        float sc = 0.f;
#pragma unroll
        for (int d = 0; d < 64; d++) sc = fmaf(qr[d], sBK[s][d], sc);
        sc *= 0.125f;
        const float nm = fmaxf(m, sc);
        const float corr = __expf(m - nm);
        const float p = __expf(sc - nm);
        Z = Z * corr + p;
#pragma unroll
        for (int d = 0; d < 64; d++) o[d] = fmaf(p, sBV[s][d], o[d] * corr);
        m = nm;
    }
    const float invZ = 1.0f / Z;
    const int b = bh >> 4, h = bh & 15;
    unsigned short* outp = attb + ((size_t)(b * TT + t)) * DD + h * DIMM;
#pragma unroll
    for (int d2 = 0; d2 < 32; d2++) {
        const uint32_t pk = (uint32_t)f2bf(o[d2 * 2] * invZ) |
                            ((uint32_t)f2bf(o[d2 * 2 + 1] * invZ) << 16);
        *(uint32_t*)&outp[d2 * 2] = pk;
    }
}

// ---------------------------------------------------------------------------
// Launcher. Workspace (float offsets), footprint = 239.1 MB (same as r3):
//   Qb 0 | Kb 1<<24 | Vb 2<<24 (fp32 V; later attb bf16 in first half,
//   WoutT bf16 at Vb+8388608) | gBK 3<<24 | gBV +512K | gA +512K
//   (WqT/WvT alias gBK/gBV until zero_k) | xb at 51388416 (8388608 floats;
//   aW/aIdx alias it after V-GEMM).
// ---------------------------------------------------------------------------
extern "C" void kernel_launch(void* const* d_in, const int* in_sizes, int n_in,
                              void* d_out, int out_size, void* d_ws, size_t ws_size,
                              hipStream_t stream)
{
    const float* x       = (const float*)d_in[0];
    const float* mask    = (const float*)d_in[1];
    const float* Wq      = (const float*)d_in[2];
    const float* Wk      = (const float*)d_in[3];
    const float* Wv      = (const float*)d_in[4];
    const float* Wout    = (const float*)d_in[5];
    const float* b_out   = (const float*)d_in[6];
    const float* planesT = (const float*)d_in[7];
    const float* protosT = (const float*)d_in[8];
    const float* ltemp   = (const float*)d_in[9];
    float* out = (float*)d_out;

    float* ws  = (float*)d_ws;
    float* Qb  = ws;
    float* Kb  = ws + (1u << 24);
    float* Vb  = ws + (2u << 24);
    float* gBK = ws + (3u << 24);
    float* gBV = gBK + 524288;
    float* gA  = gBV + 524288;
    unsigned short* WqT   = (unsigned short*)gBK;            // dead before zero_k
    unsigned short* WvT   = (unsigned short*)gBV;
    unsigned short* xb    = (unsigned short*)(ws + 51388416);
    float*          aW    = ws + 51388416;                   // aliases xb (xb dead)
    unsigned char*  aIdx  = (unsigned char*)(ws + 55582720);
    unsigned short* attb  = (unsigned short*)Vb;             // Vb dead after scatter
    unsigned short* WoutT = (unsigned short*)(ws + 41943040);// Vb second half

    const dim3 gg(16, 256);    // fp32 gemm grid
    const dim3 mg(8, 128);     // mfma gemm grid
    const dim3 tg(32, 32);     // transpose grid

    cvt_k<<<8192, 256, 0, stream>>>(x, xb);
    tr_k<<<tg, 256, 0, stream>>>(Wq, WqT);
    tr_k<<<tg, 256, 0, stream>>>(Wv, WvT);

    mgemm_k<0><<<mg, 256, 0, stream>>>(xb, WqT, mask, Qb);
    gemm_k<0><<<gg, 256, 0, stream>>>(x, Wk, mask, Kb);      // K stays fp32
    mgemm_k<0><<<mg, 256, 0, stream>>>(xb, WvT, mask, Vb);

    zero_k<<<1032, 256, 0, stream>>>(gBK);                   // gBK ++ gBV ++ gA
    assign_k<<<dim3(16, 64), 256, 0, stream>>>(Kb, planesT, protosT, ltemp, aIdx, aW, gA);
    scatter3_k<<<dim3(16, 64), 256, 0, stream>>>(Kb, Vb, aIdx, aW, gBK, gBV);

    tr_k<<<tg, 256, 0, stream>>>(Wout, WoutT);
    attn_k<<<dim3(16, 64), 256, 0, stream>>>(Qb, gBK, gBV, gA, attb);

    mgemm_k<1><<<mg, 256, 0, stream>>>(attb, WoutT, b_out, out);
}

// Round 5
// 1212.178 us; speedup vs baseline: 11.1943x; 1.2921x over previous
//
#include <hip/hip_runtime.h>
#include <math.h>
#include <stdint.h>

// Problem constants (B=4, T=4096, D=1024, H=16, DIM=64, L=8, KB=4, R=16, S=128)
#define TT   4096
#define DD   1024
#define HH   16
#define DIMM 64
#define SS   128

typedef short bf16x8 __attribute__((ext_vector_type(8)));
typedef float f32x4  __attribute__((ext_vector_type(4)));

// fp32 -> bf16 (RNE), finite inputs
__device__ __forceinline__ unsigned short f2bf(float f) {
    uint32_t u = __float_as_uint(f);
    return (unsigned short)((u + 0x7fffu + ((u >> 16) & 1u)) >> 16);
}

// async global->LDS, 16B per lane; LDS dest = uniform base + lane*16
#define GLD16(ldsp, gp) __builtin_amdgcn_global_load_lds( \
    (const __attribute__((address_space(1))) uint32_t*)(gp), \
    (__attribute__((address_space(3))) uint32_t*)(ldsp), 16, 0, 0)

// ---------------------------------------------------------------------------
// cvt: x fp32 -> bf16 (16,777,216 elements). 8 per thread.
// ---------------------------------------------------------------------------
__global__ __launch_bounds__(256) void cvt_k(const float* __restrict__ x,
                                             unsigned short* __restrict__ xb)
{
    const size_t i = ((size_t)blockIdx.x * 256 + threadIdx.x) * 8;
    const float4 a = *(const float4*)&x[i];
    const float4 b = *(const float4*)&x[i + 4];
    uint4 r;
    r.x = (uint32_t)f2bf(a.x) | ((uint32_t)f2bf(a.y) << 16);
    r.y = (uint32_t)f2bf(a.z) | ((uint32_t)f2bf(a.w) << 16);
    r.z = (uint32_t)f2bf(b.x) | ((uint32_t)f2bf(b.y) << 16);
    r.w = (uint32_t)f2bf(b.z) | ((uint32_t)f2bf(b.w) << 16);
    *(uint4*)&xb[i] = r;
}

// ---------------------------------------------------------------------------
// tr: W (1024x1024 fp32, K-major) -> WT (1024x1024 bf16, N-major: WT[n][k]).
// ---------------------------------------------------------------------------
__global__ __launch_bounds__(256) void tr_k(const float* __restrict__ W,
                                            unsigned short* __restrict__ WT)
{
    __shared__ unsigned short tile[32][33];
    const int bx = blockIdx.x * 32;   // W col (=n) base
    const int by = blockIdx.y * 32;   // W row (=k) base
    const int tx = threadIdx.x & 31, ty = threadIdx.x >> 5;  // ty 0..7
#pragma unroll
    for (int r = 0; r < 4; r++) {
        const int row = by + ty * 4 + r;
        tile[tx][ty * 4 + r] = f2bf(W[(size_t)row * 1024 + bx + tx]);
    }
    __syncthreads();
#pragma unroll
    for (int r = 0; r < 4; r++) {
        const int col = bx + ty * 4 + r;
        WT[(size_t)col * 1024 + by + tx] = tile[ty * 4 + r][tx];
    }
}

// ---------------------------------------------------------------------------
// bf16 MFMA GEMM (unchanged from r4): C(16384x1024) = A @ B with BT given
// N-major. 128x128 tile, BK=32, 4 waves, mfma_f32_16x16x32_bf16.
// MODE 0: epilogue mask[row] -> [b][h][t][d].  MODE 1: +bias, row-major.
// ---------------------------------------------------------------------------
template<int MODE>
__global__ __launch_bounds__(256) void mgemm_k(
    const unsigned short* __restrict__ Abf, const unsigned short* __restrict__ BT,
    const float* __restrict__ aux, float* __restrict__ C)
{
    __shared__ short sA[4096];   // 8 KB
    __shared__ short sB[4096];   // 8 KB
    const int tid = threadIdx.x;
    const int w  = tid >> 6;          // wave 0..3
    const int ln = tid & 63;          // lane
    const int wm = w & 1, wn = w >> 1;
    const int row0 = blockIdx.y * 128;
    const int col0 = blockIdx.x * 128;
    const int lr = ln >> 4, lc = ln & 15;

    f32x4 acc[4][4];
#pragma unroll
    for (int i = 0; i < 4; i++)
#pragma unroll
        for (int j = 0; j < 4; j++) acc[i][j] = (f32x4){0.f, 0.f, 0.f, 0.f};

    const int ia0 = 2 * w, ia1 = 2 * w + 1;
    const size_t gA0 = (size_t)(row0 + ia0 * 16 + lc) * 1024 + lr * 8;
    const size_t gA1 = (size_t)(row0 + ia1 * 16 + lc) * 1024 + lr * 8;
    const size_t gB0 = (size_t)(col0 + ia0 * 16 + lc) * 1024 + lr * 8;
    const size_t gB1 = (size_t)(col0 + ia1 * 16 + lc) * 1024 + lr * 8;

    for (int k0 = 0; k0 < 1024; k0 += 32) {
        GLD16(&sA[ia0 * 512], Abf + gA0 + k0);
        GLD16(&sA[ia1 * 512], Abf + gA1 + k0);
        GLD16(&sB[ia0 * 512], BT  + gB0 + k0);
        GLD16(&sB[ia1 * 512], BT  + gB1 + k0);
        __syncthreads();

        bf16x8 af[4], bfr[4];
#pragma unroll
        for (int ib = 0; ib < 4; ib++)
            af[ib] = *(const bf16x8*)&sA[(wm * 4 + ib) * 512 + ln * 8];
#pragma unroll
        for (int jb = 0; jb < 4; jb++)
            bfr[jb] = *(const bf16x8*)&sB[(wn * 4 + jb) * 512 + ln * 8];
#pragma unroll
        for (int ib = 0; ib < 4; ib++)
#pragma unroll
            for (int jb = 0; jb < 4; jb++)
                acc[ib][jb] = __builtin_amdgcn_mfma_f32_16x16x32_bf16(
                    af[ib], bfr[jb], acc[ib][jb], 0, 0, 0);
        __syncthreads();
    }

    if (MODE == 0) {
        const int h = col0 / 64 + wn;
#pragma unroll
        for (int ib = 0; ib < 4; ib++) {
#pragma unroll
            for (int r = 0; r < 4; r++) {
                const int gr = row0 + wm * 64 + ib * 16 + lr * 4 + r;
                const float mval = aux[gr];
                const int b = gr >> 12, t = gr & (TT - 1);
                float* base = C + (((size_t)(b * HH + h) * TT + t) * DIMM);
#pragma unroll
                for (int jb = 0; jb < 4; jb++)
                    base[jb * 16 + lc] = acc[ib][jb][r] * mval;
            }
        }
    } else {
#pragma unroll
        for (int ib = 0; ib < 4; ib++) {
#pragma unroll
            for (int r = 0; r < 4; r++) {
                const int gr = row0 + wm * 64 + ib * 16 + lr * 4 + r;
#pragma unroll
                for (int jb = 0; jb < 4; jb++) {
                    const int col = col0 + wn * 64 + jb * 16 + lc;
                    C[(size_t)gr * 1024 + col] = acc[ib][jb][r] + aux[col];
                }
            }
        }
    }
}

// ---------------------------------------------------------------------------
// fp32 GEMM (kept for K only: assignment top-2 is discrete; bf16-K noise
// would flip near-degenerate saturated-tanh gaps -> breaks threshold).
// ---------------------------------------------------------------------------
template<int MODE>
__global__ __launch_bounds__(256) void gemm_k(
    const float* __restrict__ A, const float* __restrict__ W,
    const float* __restrict__ aux, float* __restrict__ C)
{
    __shared__ float As[16][68];
    __shared__ float Ws[16][68];
    const int tid = threadIdx.x;
    const int bx = blockIdx.x, by = blockIdx.y;
    const int tx = tid & 15, ty = tid >> 4;
    const int row0 = by * 64, col0 = bx * 64;
    const int la_m = tid >> 2,        la_k = (tid & 3) * 4;
    const int lw_k = tid >> 4,        lw_n = (tid & 15) * 4;

    float acc[4][4];
#pragma unroll
    for (int i = 0; i < 4; i++)
#pragma unroll
        for (int j = 0; j < 4; j++) acc[i][j] = 0.f;

    for (int k0 = 0; k0 < 1024; k0 += 16) {
        const float4 av = *(const float4*)&A[(size_t)(row0 + la_m) * 1024 + k0 + la_k];
        const float4 wv = *(const float4*)&W[(size_t)(k0 + lw_k) * 1024 + col0 + lw_n];
        __syncthreads();
        As[la_k + 0][la_m] = av.x;
        As[la_k + 1][la_m] = av.y;
        As[la_k + 2][la_m] = av.z;
        As[la_k + 3][la_m] = av.w;
        *(float4*)&Ws[lw_k][lw_n] = wv;
        __syncthreads();
#pragma unroll
        for (int kk = 0; kk < 16; kk++) {
            const float4 af = *(const float4*)&As[kk][ty * 4];
            const float4 bf = *(const float4*)&Ws[kk][tx * 4];
            const float ar[4] = {af.x, af.y, af.z, af.w};
            const float br[4] = {bf.x, bf.y, bf.z, bf.w};
#pragma unroll
            for (int i = 0; i < 4; i++)
#pragma unroll
                for (int j = 0; j < 4; j++)
                    acc[i][j] = fmaf(ar[i], br[j], acc[i][j]);
        }
    }

    if (MODE == 0) {
        const int h = col0 >> 6;
        const int d0 = tx * 4;
#pragma unroll
        for (int i = 0; i < 4; i++) {
            const int row = row0 + ty * 4 + i;
            const float mval = aux[row];
            const int b = row >> 12, t = row & (TT - 1);
            float4 v = make_float4(acc[i][0] * mval, acc[i][1] * mval,
                                   acc[i][2] * mval, acc[i][3] * mval);
            *(float4*)&C[(((size_t)(b * HH + h) * TT + t) * DIMM) + d0] = v;
        }
    } else {
        const int c0 = col0 + tx * 4;
        const float4 bv = *(const float4*)&aux[c0];
#pragma unroll
        for (int i = 0; i < 4; i++) {
            const int row = row0 + ty * 4 + i;
            float4 v = make_float4(acc[i][0] + bv.x, acc[i][1] + bv.y,
                                   acc[i][2] + bv.z, acc[i][3] + bv.w);
            *(float4*)&C[(size_t)row * 1024 + c0] = v;
        }
    }
}

// ---------------------------------------------------------------------------
// Zero-fill gBK ++ gBV ++ gA (contiguous, 1,056,768 floats = 1032*256*4).
// ---------------------------------------------------------------------------
__global__ __launch_bounds__(256) void zero_k(float* __restrict__ p)
{
    const size_t i = ((size_t)blockIdx.x * 256 + threadIdx.x) * 4;
    *(float4*)&p[i] = make_float4(0.f, 0.f, 0.f, 0.f);
}

// ---------------------------------------------------------------------------
// Assignment (unchanged; reads fp32 Kb).
// ---------------------------------------------------------------------------
__global__ __launch_bounds__(256) void assign_k(
    const float* __restrict__ Kb, const float* __restrict__ planesT,
    const float* __restrict__ protosT, const float* __restrict__ logit_temp,
    unsigned char* __restrict__ aIdx, float* __restrict__ aW,
    float* __restrict__ gA)
{
    __shared__ float sPl[64][32];
    __shared__ float sPr[4][16];
    __shared__ float sCnt[SS];
    const int tid = threadIdx.x;
    const int tc = blockIdx.x;
    const int bh = blockIdx.y;

    for (int i = tid; i < 2048; i += 256) ((float*)sPl)[i] = planesT[i];
    if (tid < 64)  ((float*)sPr)[tid] = protosT[tid];
    if (tid < SS)  sCnt[tid] = 0.f;
    __syncthreads();

    const float scale = fminf(fmaxf(__expf(logit_temp[0]), 0.01f), 20.0f);
    const float inv_scale = 1.0f / scale;

    const int t = tc * 256 + tid;
    const float* kr = Kb + (size_t)bh * (TT * DIMM) + (size_t)t * DIMM;
    float proj[32];
#pragma unroll
    for (int p = 0; p < 32; p++) proj[p] = 0.f;
#pragma unroll 4
    for (int d4 = 0; d4 < 16; d4++) {
        const float4 kv = *(const float4*)&kr[d4 * 4];
        const float* pl = &sPl[d4 * 4][0];
#pragma unroll
        for (int p = 0; p < 32; p++)
            proj[p] += kv.x * pl[p] + kv.y * pl[32 + p] +
                       kv.z * pl[64 + p] + kv.w * pl[96 + p];
    }
#pragma unroll
    for (int p = 0; p < 32; p++) proj[p] = tanhf(proj[p]) * inv_scale;

    unsigned char idx[16];
    float wv[16];
#pragma unroll
    for (int l = 0; l < 8; l++) {
        float g[16];
#pragma unroll
        for (int r = 0; r < 16; r++)
            g[r] = proj[l * 4 + 0] * sPr[0][r] + proj[l * 4 + 1] * sPr[1][r] +
                   proj[l * 4 + 2] * sPr[2][r] + proj[l * 4 + 3] * sPr[3][r];
        float mx = g[0];
#pragma unroll
        for (int r = 1; r < 16; r++) mx = fmaxf(mx, g[r]);
        float Zs = 0.f;
#pragma unroll
        for (int r = 0; r < 16; r++) Zs += __expf(g[r] - mx);
        int a = 0; float ga = g[0];
#pragma unroll
        for (int r = 1; r < 16; r++) { if (g[r] > ga) { ga = g[r]; a = r; } }
        int b2 = (a == 0) ? 1 : 0; float gb = g[b2];
#pragma unroll
        for (int r = 0; r < 16; r++) { if (r != a && g[r] > gb) { gb = g[r]; b2 = r; } }
        const float pa = __expf(ga - mx) / Zs;
        const float pb = __expf(gb - mx) / Zs;
        const float den = pa + pb + 1e-6f;
        const float wa = pa / den, wb = pb / den;
        idx[l * 2 + 0] = (unsigned char)(l * 16 + a);  wv[l * 2 + 0] = wa;
        idx[l * 2 + 1] = (unsigned char)(l * 16 + b2); wv[l * 2 + 1] = wb;
        atomicAdd(&sCnt[l * 16 + a],  wa);
        atomicAdd(&sCnt[l * 16 + b2], wb);
    }
    const size_t off = (size_t)bh * TT + t;
    uint32_t pk[4];
#pragma unroll
    for (int j = 0; j < 4; j++)
        pk[j] = (uint32_t)idx[j * 4] | ((uint32_t)idx[j * 4 + 1] << 8) |
                ((uint32_t)idx[j * 4 + 2] << 16) | ((uint32_t)idx[j * 4 + 3] << 24);
    *(uint4*)&aIdx[off * 16] = make_uint4(pk[0], pk[1], pk[2], pk[3]);
#pragma unroll
    for (int j = 0; j < 4; j++)
        *(float4*)&aW[off * 16 + j * 4] =
            make_float4(wv[j * 4], wv[j * 4 + 1], wv[j * 4 + 2], wv[j * 4 + 3]);
    __syncthreads();
    if (tid < SS) atomicAdd(&gA[bh * SS + tid], sCnt[tid]);
}

// ---------------------------------------------------------------------------
// Scatter as MFMA GEMM: C[s][n] = sum_t P^T[s][t] * KV[t][n]  (s=128, n=128,
// t = K-dim). Grid (8 t-chunks of 512, 64 bh); per block 8 sub-chunks of 64
// tokens. Per sub-chunk: zero+scatter P^T into bf16 A-frag LDS layout, stage
// KV (transpose fp32->bf16) into B-frag layout (lane<->column: 2-way-free
// bank writes), 2 K-steps x 16 mfma_bf16 per wave. fp32 atomicAdd fold-out.
// Numerics: bf16 on P/KV enters bucket *averages* -> ~6e-5/entry, safe.
// ---------------------------------------------------------------------------
__global__ __launch_bounds__(256) void scatter4_k(
    const float* __restrict__ Kb, const float* __restrict__ Vb,
    const unsigned char* __restrict__ aIdx, const float* __restrict__ aW,
    float* __restrict__ gBK, float* __restrict__ gBV)
{
    __shared__ short sA[8192];   // P^T bf16 (16 KB): A(s,k) frag layout
    __shared__ short sB[8192];   // KV  bf16 (16 KB): B(k,n) frag layout
    const int tid = threadIdx.x;
    const int tc = blockIdx.x;   // 8
    const int bh = blockIdx.y;   // 64
    const int w  = tid >> 6, ln = tid & 63;
    const int wm = w & 1, wn = w >> 1;

    f32x4 acc[4][4];
#pragma unroll
    for (int i = 0; i < 4; i++)
#pragma unroll
        for (int j = 0; j < 4; j++) acc[i][j] = (f32x4){0.f, 0.f, 0.f, 0.f};

    // staging role: one column per thread (coalesced row reads, 2-way LDS banks)
    const int scol = tid & 127;          // 0..127: K cols 0-63 | V cols 64-127
    const int stg  = tid >> 7;           // token half: 0..1
    const float* srcrow = (scol < 64)
        ? Kb + (size_t)bh * (TT * DIMM) + scol
        : Vb + (size_t)bh * (TT * DIMM) + (scol - 64);
    const int bchunk = (scol >> 4);       // n>>4
    const int bslot8 = (scol & 15) * 8;
    // P role: token ptt (0..63), pair-group pg (0..3)
    const int ptt = tid >> 2, pg = tid & 3;

    for (int c = 0; c < 8; c++) {
        const int t0 = tc * 512 + c * 64;
        __syncthreads();                              // prior MFMA reads done
        {   // zero P^T region (16 KB)
            const uint4 z = make_uint4(0u, 0u, 0u, 0u);
#pragma unroll
            for (int r = 0; r < 4; r++)
                *(uint4*)&sA[(r * 256 + tid) * 8] = z;
        }
        __syncthreads();                              // zero visible
        // stage KV: 32 tokens per thread, fixed column; B(k=tt, n=scol)
#pragma unroll 8
        for (int r = 0; r < 32; r++) {
            const int tt = stg * 32 + r;
            const float v = srcrow[(size_t)(t0 + tt) * DIMM];
            sB[((tt >> 5) * 8 + bchunk) * 512 + ((tt >> 3) & 3) * 128 +
               bslot8 + (tt & 7)] = f2bf(v);
        }
        {   // scatter P^T: A(s = idx, k = ptt)
            const size_t off = (size_t)bh * TT + (t0 + ptt);
            const uint32_t pk = ((const uint32_t*)aIdx)[off * 4 + pg];
            const float4 wv = *(const float4*)&aW[off * 16 + pg * 4];
            const float w4[4] = {wv.x, wv.y, wv.z, wv.w};
#pragma unroll
            for (int q = 0; q < 4; q++) {
                const int s = (pk >> (8 * q)) & 255;
                sA[((ptt >> 5) * 8 + (s >> 4)) * 512 + ((ptt >> 3) & 3) * 128 +
                   (s & 15) * 8 + (ptt & 7)] = f2bf(w4[q]);
            }
        }
        __syncthreads();                              // tiles ready
#pragma unroll
        for (int ks = 0; ks < 2; ks++) {
            bf16x8 af[4], bfr[4];
#pragma unroll
            for (int ib = 0; ib < 4; ib++)
                af[ib] = *(const bf16x8*)&sA[(ks * 8 + wm * 4 + ib) * 512 + ln * 8];
#pragma unroll
            for (int jb = 0; jb < 4; jb++)
                bfr[jb] = *(const bf16x8*)&sB[(ks * 8 + wn * 4 + jb) * 512 + ln * 8];
#pragma unroll
            for (int ib = 0; ib < 4; ib++)
#pragma unroll
                for (int jb = 0; jb < 4; jb++)
                    acc[ib][jb] = __builtin_amdgcn_mfma_f32_16x16x32_bf16(
                        af[ib], bfr[jb], acc[ib][jb], 0, 0, 0);
        }
    }

    // fold partials (8 blocks per bh contend per address)
    const int lr = ln >> 4, lc = ln & 15;
#pragma unroll
    for (int ib = 0; ib < 4; ib++) {
#pragma unroll
        for (int r = 0; r < 4; r++) {
            const int s = wm * 64 + ib * 16 + lr * 4 + r;
#pragma unroll
            for (int jb = 0; jb < 4; jb++) {
                const int col = wn * 64 + jb * 16 + lc;
                if (col < 64)
                    atomicAdd(&gBK[(size_t)bh * (SS * DIMM) + s * DIMM + col],
                              acc[ib][jb][r]);
                else
                    atomicAdd(&gBV[(size_t)bh * (SS * DIMM) + s * DIMM + (col - 64)],
                              acc[ib][jb][r]);
            }
        }
    }
}

// ---------------------------------------------------------------------------
// Attention (writes bf16 att in (b, t, h*d) row-major for the out-GEMM).
// ---------------------------------------------------------------------------
__global__ __launch_bounds__(256) void attn_k(
    const float* __restrict__ Qb, const float* __restrict__ gBK,
    const float* __restrict__ gBV, const float* __restrict__ gA,
    unsigned short* __restrict__ attb)
{
    __shared__ float sBK[SS][DIMM];
    __shared__ float sBV[SS][DIMM];
    const int tid = threadIdx.x;
    const int tc = blockIdx.x;
    const int bh = blockIdx.y;
    float* sk = &sBK[0][0];
    float* sv = &sBV[0][0];
    for (int i = tid * 4; i < SS * DIMM; i += 1024) {
        const int s = i >> 6;
        const float inv = 1.0f / (gA[bh * SS + s] + 1e-6f);
        float4 kv = *(const float4*)&gBK[(size_t)bh * (SS * DIMM) + i];
        float4 vv = *(const float4*)&gBV[(size_t)bh * (SS * DIMM) + i];
        kv.x *= inv; kv.y *= inv; kv.z *= inv; kv.w *= inv;
        vv.x *= inv; vv.y *= inv; vv.z *= inv; vv.w *= inv;
        *(float4*)&sk[i] = kv;
        *(float4*)&sv[i] = vv;
    }
    __syncthreads();

    const int t = tc * 256 + tid;
    const float* q = Qb + (size_t)bh * (TT * DIMM) + (size_t)t * DIMM;
    float qr[64];
#pragma unroll
    for (int d4 = 0; d4 < 16; d4++) {
        const float4 v = *(const float4*)&q[d4 * 4];
        qr[d4 * 4 + 0] = v.x; qr[d4 * 4 + 1] = v.y; qr[d4 * 4 + 2] = v.z; qr[d4 * 4 + 3] = v.w;
    }
    float m = -INFINITY, Z = 0.f, o[64];
#pragma unroll
    for (int d = 0; d < 64; d++) o[d] = 0.f;

    for (int s = 0; s < SS; s++) {
        float sc = 0.f;
#pragma unroll
        for (int d = 0; d < 64; d++) sc = fmaf(qr[d], sBK[s][d], sc);
        sc *= 0.125f;
        const float nm = fmaxf(m, sc);
        const float corr = __expf(m - nm);
        const float p = __expf(sc - nm);
        Z = Z * corr + p;
#pragma unroll
        for (int d = 0; d < 64; d++) o[d] = fmaf(p, sBV[s][d], o[d] * corr);
        m = nm;
    }
    const float invZ = 1.0f / Z;
    const int b = bh >> 4, h = bh & 15;
    unsigned short* outp = attb + ((size_t)(b * TT + t)) * DD + h * DIMM;
#pragma unroll
    for (int d2 = 0; d2 < 32; d2++) {
        const uint32_t pk = (uint32_t)f2bf(o[d2 * 2] * invZ) |
                            ((uint32_t)f2bf(o[d2 * 2 + 1] * invZ) << 16);
        *(uint32_t*)&outp[d2 * 2] = pk;
    }
}

// ---------------------------------------------------------------------------
// Launcher. Workspace (float offsets), footprint = 239.1 MB (same as r4):
//   Qb 0 | Kb 1<<24 | Vb 2<<24 (fp32 V; later attb bf16 in first half,
//   WoutT bf16 at Vb+8388608) | gBK 3<<24 | gBV +512K | gA +512K
//   (WqT/WvT alias gBK/gBV until zero_k) | xb at 51388416 (8388608 floats;
//   aW/aIdx alias it after V-GEMM).
// ---------------------------------------------------------------------------
extern "C" void kernel_launch(void* const* d_in, const int* in_sizes, int n_in,
                              void* d_out, int out_size, void* d_ws, size_t ws_size,
                              hipStream_t stream)
{
    const float* x       = (const float*)d_in[0];
    const float* mask    = (const float*)d_in[1];
    const float* Wq      = (const float*)d_in[2];
    const float* Wk      = (const float*)d_in[3];
    const float* Wv      = (const float*)d_in[4];
    const float* Wout    = (const float*)d_in[5];
    const float* b_out   = (const float*)d_in[6];
    const float* planesT = (const float*)d_in[7];
    const float* protosT = (const float*)d_in[8];
    const float* ltemp   = (const float*)d_in[9];
    float* out = (float*)d_out;

    float* ws  = (float*)d_ws;
    float* Qb  = ws;
    float* Kb  = ws + (1u << 24);
    float* Vb  = ws + (2u << 24);
    float* gBK = ws + (3u << 24);
    float* gBV = gBK + 524288;
    float* gA  = gBV + 524288;
    unsigned short* WqT   = (unsigned short*)gBK;            // dead before zero_k
    unsigned short* WvT   = (unsigned short*)gBV;
    unsigned short* xb    = (unsigned short*)(ws + 51388416);
    float*          aW    = ws + 51388416;                   // aliases xb (xb dead)
    unsigned char*  aIdx  = (unsigned char*)(ws + 55582720);
    unsigned short* attb  = (unsigned short*)Vb;             // Vb dead after scatter
    unsigned short* WoutT = (unsigned short*)(ws + 41943040);// Vb second half

    const dim3 gg(16, 256);    // fp32 gemm grid
    const dim3 mg(8, 128);     // mfma gemm grid
    const dim3 tg(32, 32);     // transpose grid

    cvt_k<<<8192, 256, 0, stream>>>(x, xb);
    tr_k<<<tg, 256, 0, stream>>>(Wq, WqT);
    tr_k<<<tg, 256, 0, stream>>>(Wv, WvT);

    mgemm_k<0><<<mg, 256, 0, stream>>>(xb, WqT, mask, Qb);
    gemm_k<0><<<gg, 256, 0, stream>>>(x, Wk, mask, Kb);      // K stays fp32
    mgemm_k<0><<<mg, 256, 0, stream>>>(xb, WvT, mask, Vb);

    zero_k<<<1032, 256, 0, stream>>>(gBK);                   // gBK ++ gBV ++ gA
    assign_k<<<dim3(16, 64), 256, 0, stream>>>(Kb, planesT, protosT, ltemp, aIdx, aW, gA);
    scatter4_k<<<dim3(8, 64), 256, 0, stream>>>(Kb, Vb, aIdx, aW, gBK, gBV);

    tr_k<<<tg, 256, 0, stream>>>(Wout, WoutT);
    attn_k<<<dim3(16, 64), 256, 0, stream>>>(Qb, gBK, gBV, gA, attb);

    mgemm_k<1><<<mg, 256, 0, stream>>>(attb, WoutT, b_out, out);
}